// Round 3
// baseline (15915.125 us; speedup 1.0000x reference)
//
#include <hip/hip_runtime.h>
#include <cstdint>

// Problem constants
#define Bsz 2048
#define Ssz 50
#define Esz 256
#define Hsz 512
#define Wsz 256
#define Lsz 50
#define Vsz 51

// JAX RNG semantics: 1 = threefry_partitionable (jax >= 0.4.36 default), 0 = original
#define JAX_THREEFRY_PARTITIONABLE 1

// ---------------- threefry2x32 (20 rounds), key words (k0,k1) ----------------
__host__ __device__ __forceinline__ void threefry2x32_hd(
    unsigned k0, unsigned k1, unsigned x0, unsigned x1,
    unsigned& o0, unsigned& o1) {
  unsigned ks2 = k0 ^ k1 ^ 0x1BD11BDAu;
  x0 += k0; x1 += k1;
#define TF_RND(r) { x0 += x1; x1 = (x1 << (r)) | (x1 >> (32 - (r))); x1 ^= x0; }
  TF_RND(13) TF_RND(15) TF_RND(26) TF_RND(6)
  x0 += k1; x1 += ks2 + 1u;
  TF_RND(17) TF_RND(29) TF_RND(16) TF_RND(24)
  x0 += ks2; x1 += k0 + 2u;
  TF_RND(13) TF_RND(15) TF_RND(26) TF_RND(6)
  x0 += k0; x1 += k1 + 3u;
  TF_RND(17) TF_RND(29) TF_RND(16) TF_RND(24)
  x0 += k1; x1 += ks2 + 4u;
  TF_RND(13) TF_RND(15) TF_RND(26) TF_RND(6)
  x0 += ks2; x1 += k0 + 5u;
#undef TF_RND
  o0 = x0; o1 = x1;
}

// ---- prep: gates W pack ----
// WgP float layout: [jBlk 0..15][k 0..511][Jloc 0..31][g 0..3]
//   value = Whh[g*512 + (jBlk*32+Jloc)][k]
// Wave reads 8 float4 (128B) contiguous per (jBlk,k,jw8) -> uniform address.
__global__ __launch_bounds__(256) void prep_gpack(const float* __restrict__ src,
                                                  float* __restrict__ dst) {
  int o = blockIdx.x * 256 + threadIdx.x;   // < 16*512*32*4 = 1M
  int g = o & 3;
  int Jloc = (o >> 2) & 31;
  int k = (o >> 7) & 511;
  int jBlk = o >> 16;
  int j = jBlk * 32 + Jloc;
  dst[o] = src[(size_t)(g * 512 + j) * 512 + k];
}

// ---- prep: blend W pack: [wBlk 0..7][k 0..511][wloc 0..31] ----
//   value = Wm[(wBlk*32+wloc)][k]
__global__ __launch_bounds__(256) void prep_bpack(const float* __restrict__ src,
                                                  float* __restrict__ dst) {
  int o = blockIdx.x * 256 + threadIdx.x;   // < 8*512*32 = 131072
  int wloc = o & 31;
  int k = (o >> 5) & 511;
  int wBlk = o >> 14;
  dst[o] = src[(size_t)(wBlk * 32 + wloc) * 512 + k];
}

// ---------------- prep: encInP[v][j][g] = emb[v].Wih[g*512+j] + bih + bhh ----
__global__ __launch_bounds__(256) void prep_encin(
    const float* __restrict__ emb, const float* __restrict__ Wih,
    const float* __restrict__ bih, const float* __restrict__ bhh,
    float* __restrict__ encInP) {
  int wid = blockIdx.x * 4 + (threadIdx.x >> 6);
  int lane = threadIdx.x & 63;
  if (wid >= Vsz * 2048) return;
  int v = wid >> 11, col = wid & 2047;
  float4 e = ((const float4*)emb)[v * 64 + lane];
  float4 w = ((const float4*)Wih)[col * 64 + lane];
  float d = e.x * w.x + e.y * w.y + e.z * w.z + e.w * w.w;
  for (int off = 32; off; off >>= 1) d += __shfl_xor(d, off);
  if (lane == 0) {
    int g = col >> 9, j = col & 511;
    encInP[(size_t)v * 2048 + j * 4 + g] = d + bih[col] + bhh[col];
  }
}

// ---------------- prep: dbiasP[j][g] = dec_bih + dec_bhh ----------------
__global__ __launch_bounds__(256) void prep_dbias(const float* __restrict__ a,
                                                  const float* __restrict__ b,
                                                  float* __restrict__ dst) {
  int col = blockIdx.x * 256 + threadIdx.x;  // < 2048
  int g = col >> 9, j = col & 511;
  dst[j * 4 + g] = a[col] + b[col];
}

// ---------------- fused gates GEMM + LSTM cell ----------------
// Block = 64 b x 32 J (J = gate-float4 col). 256 thr = 4 waves; wave owns 8 J
// (readfirstlane -> W addresses provably wave-uniform -> 1 line/request);
// thread = 1 b (lane) x 8 gate-float4 accums.
// h staged in LDS 64x64 chunks with float4-granule XOR swizzle
// F' = (b<<4) | (kf4 ^ (b&15)): staging writes stay wave-contiguous per-row
// AND per-lane-row ds_read_b128 is bank-balanced (8 lanes/bank-quad = the
// conflict-free b128 baseline). Fixes r2's 64-line h scatter.
__global__ __launch_bounds__(256) void gates_step(
    const float* __restrict__ hin, const float* __restrict__ Wg,
    const float* __restrict__ addtab, const int* __restrict__ input, int tstep,
    float* __restrict__ hout, float* __restrict__ cio) {
  __shared__ float4 hs[1024];   // 16 KB: 64 b x 16 f4, swizzled
  const int t = threadIdx.x;
  const int lane = t & 63;
  const int wave = t >> 6;
  const int jBlk = blockIdx.x & 15;            // 16 J-blocks of 32
  const int bBase = (blockIdx.x >> 4) * 64;    // 32 b-blocks of 64
  const int jw8 = __builtin_amdgcn_readfirstlane(wave << 3);  // 0,8,16,24
  const int b = bBase + lane;
  const int swz = lane & 15;

  // hoisted epilogue row pointer (latency hides under the k-loop)
  const float4* arow = input
      ? (const float4*)(addtab + (size_t)input[(size_t)b * Ssz + tstep] * 2048)
      : (const float4*)addtab;

  const float4* wbase = (const float4*)Wg + ((size_t)jBlk * 512) * 32 + jw8;
  const float4* hf4 = (const float4*)hin;      // [row*128 + f4]

  float4 acc[8];
#pragma unroll
  for (int jj = 0; jj < 8; ++jj) acc[jj] = make_float4(0.f, 0.f, 0.f, 0.f);

#pragma unroll 1
  for (int c = 0; c < 8; ++c) {
    if (c) __syncthreads();      // WAR: all reads of prev chunk done
    // stage: 4 float4 per thread; write-instr q is 1KB wave-contiguous
#pragma unroll
    for (int q = 0; q < 4; ++q) {
      int bl = (wave * 4 + q) * 4 + (lane >> 4);
      int kf4 = lane & 15;
      float4 v = hf4[(size_t)(bBase + bl) * 128 + c * 16 + kf4];
      hs[(bl << 4) | (kf4 ^ (bl & 15))] = v;
    }
    __syncthreads();
    const float4* wc = wbase + (size_t)(c * 64) * 32;
#pragma unroll 4
    for (int g4 = 0; g4 < 16; ++g4) {
      float4 hv = hs[(lane << 4) | (g4 ^ swz)];
      const float4* wk = wc + (size_t)(g4 * 4) * 32;
#pragma unroll
      for (int kk = 0; kk < 4; ++kk) {
        float hsv = (kk == 0) ? hv.x : (kk == 1) ? hv.y : (kk == 2) ? hv.z : hv.w;
        const float4* wkk = wk + kk * 32;
#pragma unroll
        for (int jj = 0; jj < 8; ++jj) {
          float4 w = wkk[jj];
          acc[jj].x = fmaf(hsv, w.x, acc[jj].x);
          acc[jj].y = fmaf(hsv, w.y, acc[jj].y);
          acc[jj].z = fmaf(hsv, w.z, acc[jj].z);
          acc[jj].w = fmaf(hsv, w.w, acc[jj].w);
        }
      }
    }
  }

  // epilogue: this thread owns (b, J0..J0+7)
  const int J0 = jBlk * 32 + jw8;
  float4 av[8];
#pragma unroll
  for (int jj = 0; jj < 8; ++jj) av[jj] = arow[J0 + jj];
  float4 cv0 = *(const float4*)(cio + (size_t)b * Hsz + J0);
  float4 cv1 = *(const float4*)(cio + (size_t)b * Hsz + J0 + 4);
  float cin[8] = {cv0.x, cv0.y, cv0.z, cv0.w, cv1.x, cv1.y, cv1.z, cv1.w};
  float cn[8], hn[8];
#pragma unroll
  for (int jj = 0; jj < 8; ++jj) {
    float gi = acc[jj].x + av[jj].x;
    float gf = acc[jj].y + av[jj].y;
    float gg = acc[jj].z + av[jj].z;
    float go = acc[jj].w + av[jj].w;
    float si = 1.0f / (1.0f + expf(-gi));
    float sf = 1.0f / (1.0f + expf(-gf));
    float sg = tanhf(gg);
    float so = 1.0f / (1.0f + expf(-go));
    float c2 = sf * cin[jj] + si * sg;
    cn[jj] = c2;
    hn[jj] = so * tanhf(c2);
  }
  *(float4*)(cio + (size_t)b * Hsz + J0)     = make_float4(cn[0], cn[1], cn[2], cn[3]);
  *(float4*)(cio + (size_t)b * Hsz + J0 + 4) = make_float4(cn[4], cn[5], cn[6], cn[7]);
  *(float4*)(hout + (size_t)b * Hsz + J0)     = make_float4(hn[0], hn[1], hn[2], hn[3]);
  *(float4*)(hout + (size_t)b * Hsz + J0 + 4) = make_float4(hn[4], hn[5], hn[6], hn[7]);
}

// ---------------- blend GEMM: out[b][w] = sum_k h[b][k]*Wm[w][k] -------------
// Same structure: 256 blocks = 32 bBlk x 8 wBlk(32 w); wave owns 8 w.
__global__ __launch_bounds__(256) void blend_gemm(
    const float* __restrict__ hin, const float* __restrict__ Wb,
    float* __restrict__ out, int rowStride) {
  __shared__ float4 hs[1024];
  const int t = threadIdx.x;
  const int lane = t & 63;
  const int wave = t >> 6;
  const int wBlk = blockIdx.x & 7;             // 8 w-blocks of 32
  const int bBase = (blockIdx.x >> 3) * 64;    // 32 b-blocks of 64
  const int jw8 = __builtin_amdgcn_readfirstlane(wave << 3);
  const int b = bBase + lane;
  const int swz = lane & 15;

  const float4* wb = (const float4*)Wb + ((size_t)wBlk * 512) * 8 + (jw8 >> 2);
  const float4* hf4 = (const float4*)hin;

  float4 a0 = make_float4(0.f, 0.f, 0.f, 0.f);
  float4 a1 = a0;

#pragma unroll 1
  for (int c = 0; c < 8; ++c) {
    if (c) __syncthreads();
#pragma unroll
    for (int q = 0; q < 4; ++q) {
      int bl = (wave * 4 + q) * 4 + (lane >> 4);
      int kf4 = lane & 15;
      float4 v = hf4[(size_t)(bBase + bl) * 128 + c * 16 + kf4];
      hs[(bl << 4) | (kf4 ^ (bl & 15))] = v;
    }
    __syncthreads();
#pragma unroll 4
    for (int g4 = 0; g4 < 16; ++g4) {
      float4 hv = hs[(lane << 4) | (g4 ^ swz)];
#pragma unroll
      for (int kk = 0; kk < 4; ++kk) {
        float hsv = (kk == 0) ? hv.x : (kk == 1) ? hv.y : (kk == 2) ? hv.z : hv.w;
        const float4* wkk = wb + (size_t)(c * 64 + g4 * 4 + kk) * 8;
        float4 w0 = wkk[0];
        float4 w1 = wkk[1];
        a0.x = fmaf(hsv, w0.x, a0.x); a0.y = fmaf(hsv, w0.y, a0.y);
        a0.z = fmaf(hsv, w0.z, a0.z); a0.w = fmaf(hsv, w0.w, a0.w);
        a1.x = fmaf(hsv, w1.x, a1.x); a1.y = fmaf(hsv, w1.y, a1.y);
        a1.z = fmaf(hsv, w1.z, a1.z); a1.w = fmaf(hsv, w1.w, a1.w);
      }
    }
  }
  float* op = out + (size_t)b * rowStride + wBlk * 32 + jw8;
  *(float4*)op = a0;
  *(float4*)(op + 4) = a1;
}

// ---------------- scores + log_softmax + gumbel sample + mask ----------------
__global__ __launch_bounds__(256) void scores_sample(
    const float* __restrict__ b1, const float* __restrict__ b2,
    const float* __restrict__ vt, unsigned long long* __restrict__ mask,
    float* __restrict__ probs, float* __restrict__ tour,
    int stepk, unsigned kA, unsigned kB) {
  __shared__ float b2s[256];
  __shared__ float vts[256];
  __shared__ float sc[52];
  const int t = threadIdx.x, b = blockIdx.x;
  b2s[t] = b2[(size_t)b * Wsz + t];
  vts[t] = vt[t];
  __syncthreads();
  const int wave = t >> 6, lane = t & 63;
  for (int s = wave; s < Ssz; s += 4) {
    const float* row = b1 + ((size_t)b * Ssz + s) * Wsz;
    float v = 0.f;
#pragma unroll
    for (int q = 0; q < 4; ++q) {
      int w = lane + 64 * q;
      v += vts[w] * tanhf(row[w] + b2s[w]);
    }
    for (int off = 32; off; off >>= 1) v += __shfl_xor(v, off);
    if (lane == 0) sc[s] = v;
  }
  __syncthreads();
  if (wave == 0) {
    unsigned long long m = mask[b];
    float x = (lane < Ssz) ? sc[lane] : -INFINITY;
    if (lane < Ssz && ((m >> lane) & 1ull)) x = -100000.0f;
    float mv = x;
    for (int off = 32; off; off >>= 1) mv = fmaxf(mv, __shfl_xor(mv, off));
    float sh = x - mv;
    float e = (lane < Ssz) ? expf(sh) : 0.f;
    float ssum = e;
    for (int off = 32; off; off >>= 1) ssum += __shfl_xor(ssum, off);
    float lg = logf(ssum);
    float logp = sh - lg;
    if (lane < Ssz) probs[(size_t)b * (Lsz * Ssz) + stepk * Ssz + lane] = logp;

    float val = -INFINITY;
    if (lane < Ssz) {
      unsigned j = (unsigned)(b * Ssz + lane);
      unsigned o0, o1, bits;
#if JAX_THREEFRY_PARTITIONABLE
      threefry2x32_hd(kA, kB, 0u, j, o0, o1);
      bits = o0 ^ o1;
#else
      if (j < 51200u) { threefry2x32_hd(kA, kB, j, j + 51200u, o0, o1); bits = o0; }
      else           { threefry2x32_hd(kA, kB, j - 51200u, j, o0, o1); bits = o1; }
#endif
      float f = __uint_as_float((bits >> 9) | 0x3F800000u) - 1.0f;
      float u = fmaxf(1.17549435e-38f, f + 1.17549435e-38f);
      val = logp - logf(-logf(u));
    }
    int idx = lane;
    for (int off = 32; off; off >>= 1) {
      float ov = __shfl_xor(val, off);
      int oi = __shfl_xor(idx, off);
      if (ov > val || (ov == val && oi < idx)) { val = ov; idx = oi; }
    }
    if (lane == 0) {
      tour[(size_t)b * Lsz + stepk] = (float)idx;
      mask[b] = m | (1ull << idx);
    }
  }
}

extern "C" void kernel_launch(void* const* d_in, const int* in_sizes, int n_in,
                              void* d_out, int out_size, void* d_ws, size_t ws_size,
                              hipStream_t stream) {
  (void)in_sizes; (void)n_in; (void)out_size; (void)ws_size;
  const int*   input = (const int*)d_in[0];
  const float* emb   = (const float*)d_in[1];
  const float* eWih  = (const float*)d_in[2];
  const float* eWhh  = (const float*)d_in[3];
  const float* ebih  = (const float*)d_in[4];
  const float* ebhh  = (const float*)d_in[5];
  /* d_in[6] dec_Wih unused: decoder input is always zero */
  const float* dWhh  = (const float*)d_in[7];
  const float* dbih  = (const float*)d_in[8];
  const float* dbhh  = (const float*)d_in[9];
  const float* W1    = (const float*)d_in[10];
  const float* W2    = (const float*)d_in[11];
  const float* vt    = (const float*)d_in[12];
  float* outF = (float*)d_out;

  float* wsf = (float*)d_ws;
  size_t o = 0;
  float* WgE  = wsf + o; o += (size_t)16 * 512 * 32 * 4;  // enc gates W pack (4MB)
  float* WgD  = wsf + o; o += (size_t)16 * 512 * 32 * 4;  // dec gates W pack
  float* Wb1  = wsf + o; o += (size_t)8 * 512 * 32;       // W1 blend pack
  float* Wb2  = wsf + o; o += (size_t)8 * 512 * 32;       // W2 blend pack
  float* encInP = wsf + o; o += (size_t)Vsz * 2048;
  float* dbiasP = wsf + o; o += 2048;
  float* hA  = wsf + o; o += (size_t)Bsz * Hsz;
  float* hB  = wsf + o; o += (size_t)Bsz * Hsz;
  float* cE  = wsf + o; o += (size_t)Bsz * Hsz;
  float* hdA = wsf + o; o += (size_t)Bsz * Hsz;
  float* hdB = wsf + o; o += (size_t)Bsz * Hsz;
  float* b2  = wsf + o; o += (size_t)Bsz * Wsz;
  float* b1  = wsf + o; o += (size_t)Bsz * Ssz * Wsz;
  unsigned long long* maskp = (unsigned long long*)(wsf + o); o += Bsz * 2;

  hipMemsetAsync(hA, 0, (size_t)Bsz * Hsz * 4, stream);
  hipMemsetAsync(cE, 0, (size_t)Bsz * Hsz * 4, stream);
  hipMemsetAsync(hdA, 0, (size_t)Bsz * Hsz * 4, stream);
  hipMemsetAsync(maskp, 0, (size_t)Bsz * 8, stream);

  prep_gpack<<<4096, 256, 0, stream>>>(eWhh, WgE);
  prep_gpack<<<4096, 256, 0, stream>>>(dWhh, WgD);
  prep_bpack<<<512, 256, 0, stream>>>(W1, Wb1);
  prep_bpack<<<512, 256, 0, stream>>>(W2, Wb2);
  prep_encin<<<(Vsz * 2048) / 4, 256, 0, stream>>>(emb, eWih, ebih, ebhh, encInP);
  prep_dbias<<<8, 256, 0, stream>>>(dbih, dbhh, dbiasP);

  // host-side: step keys = jax.random.split(jax.random.key(42), 50)
  unsigned kAh[Lsz], kBh[Lsz];
  for (int k = 0; k < Lsz; ++k) {
#if JAX_THREEFRY_PARTITIONABLE
    threefry2x32_hd(0u, 42u, 0u, (unsigned)k, kAh[k], kBh[k]);
#else
    unsigned a0, a1, c0, c1;
    if (k < 25) {
      threefry2x32_hd(0u, 42u, 2u * k,      2u * k + 50u, a0, a1); kAh[k] = a0;
      threefry2x32_hd(0u, 42u, 2u * k + 1u, 2u * k + 51u, c0, c1); kBh[k] = c0;
    } else {
      threefry2x32_hd(0u, 42u, 2u * k - 50u, 2u * k,      a0, a1); kAh[k] = a1;
      threefry2x32_hd(0u, 42u, 2u * k - 49u, 2u * k + 1u, c0, c1); kBh[k] = c1;
    }
#endif
  }

  // encoder
  float* hr = hA; float* hw = hB;
  for (int t = 0; t < Ssz; ++t) {
    gates_step<<<512, 256, 0, stream>>>(hr, WgE, encInP, input, t, hw, cE);
    blend_gemm<<<256, 256, 0, stream>>>(hw, Wb1, b1 + (size_t)t * Wsz, Ssz * Wsz);
    float* tp = hr; hr = hw; hw = tp;
  }
  // decoder init: c0 = last encoder h (alias, no copy), h0 = 0 (hdA), mask = 0
  float* cD = hr;

  float* dr = hdA; float* dw = hdB;
  for (int k = 0; k < Lsz; ++k) {
    gates_step<<<512, 256, 0, stream>>>(dr, WgD, dbiasP, nullptr, 0, dw, cD);
    blend_gemm<<<256, 256, 0, stream>>>(dw, Wb2, b2, Wsz);
    scores_sample<<<Bsz, 256, 0, stream>>>(b1, b2, vt, maskp, outF,
                                           outF + (size_t)Bsz * Lsz * Ssz,
                                           k, kAh[k], kBh[k]);
    float* tp = dr; dr = dw; dw = tp;
  }
}

// Round 4
// 5893.966 us; speedup vs baseline: 2.7002x; 2.7002x over previous
//
#include <hip/hip_runtime.h>
#include <cstdint>

// Problem constants
#define Bsz 2048
#define Ssz 50
#define Esz 256
#define Hsz 512
#define Wsz 256
#define Lsz 50
#define Vsz 51
#define KC 48   // k-chunks of 32 over K_eff = 1536 (fp16x3 split)

// JAX RNG semantics: 1 = threefry_partitionable (jax >= 0.4.36 default), 0 = original
#define JAX_THREEFRY_PARTITIONABLE 1

typedef _Float16 f16;
typedef _Float16 f16x8 __attribute__((ext_vector_type(8)));
typedef float f32x4 __attribute__((ext_vector_type(4)));

// ---------------- threefry2x32 (20 rounds), key words (k0,k1) ----------------
__host__ __device__ __forceinline__ void threefry2x32_hd(
    unsigned k0, unsigned k1, unsigned x0, unsigned x1,
    unsigned& o0, unsigned& o1) {
  unsigned ks2 = k0 ^ k1 ^ 0x1BD11BDAu;
  x0 += k0; x1 += k1;
#define TF_RND(r) { x0 += x1; x1 = (x1 << (r)) | (x1 >> (32 - (r))); x1 ^= x0; }
  TF_RND(13) TF_RND(15) TF_RND(26) TF_RND(6)
  x0 += k1; x1 += ks2 + 1u;
  TF_RND(17) TF_RND(29) TF_RND(16) TF_RND(24)
  x0 += ks2; x1 += k0 + 2u;
  TF_RND(13) TF_RND(15) TF_RND(26) TF_RND(6)
  x0 += k0; x1 += k1 + 3u;
  TF_RND(17) TF_RND(29) TF_RND(16) TF_RND(24)
  x0 += k1; x1 += ks2 + 4u;
  TF_RND(13) TF_RND(15) TF_RND(26) TF_RND(6)
  x0 += ks2; x1 += k0 + 5u;
#undef TF_RND
  o0 = x0; o1 = x1;
}

// ---- prep: gates W fragment pack ----
// B' layout: [ntile 0..127][kc 0..47][lane 0..63][e 0..7] f16, where the
// mfma_f32_16x16x32_f16 B-frag for (ntile,kc) has lane l = kg*16 + c holding
// Wf16[n = ntile*16 + c][k = kc*32 + kg*8 + e].  n' = j*4+g (gate-interleaved),
// Wf16 k-blocks = [Whi | Whi | Wlo*2048] (fp16x3; third term rescaled so the
// lo-part stays in fp16 normal range -> immune to MFMA denorm flush).
__global__ __launch_bounds__(512) void prep_gfrag(const float* __restrict__ Whh,
                                                  f16* __restrict__ dst) {
  int blk = blockIdx.x;            // ntile*48 + kc   (grid 128*48 = 6144)
  int ntile = blk / KC, kc = blk % KC;
  int t = threadIdx.x;             // 512 = l*8 + e
  int l = t >> 3, e = t & 7;
  int c = l & 15, kg = l >> 4;
  int n = ntile * 16 + c;          // n' in [0,2048)
  int keff = kc * 32 + kg * 8 + e;
  int kblk = keff >> 9, k = keff & 511;
  int j = n >> 2, g = n & 3;
  float w = Whh[(size_t)(g * 512 + j) * 512 + k];
  f16 hi = (f16)w;
  float lo = w - (float)hi;
  f16 val = (kblk < 2) ? hi : (f16)(lo * 2048.0f);
  dst[(size_t)blk * 512 + t] = val;
}

// ---- prep: blend W fragment pack: [wtile 0..15][kc][lane][e], n = w direct --
__global__ __launch_bounds__(512) void prep_bfrag(const float* __restrict__ Wm,
                                                  f16* __restrict__ dst) {
  int blk = blockIdx.x;            // wtile*48 + kc   (grid 16*48 = 768)
  int wtile = blk / KC, kc = blk % KC;
  int t = threadIdx.x;
  int l = t >> 3, e = t & 7;
  int c = l & 15, kg = l >> 4;
  int n = wtile * 16 + c;          // w in [0,256)
  int keff = kc * 32 + kg * 8 + e;
  int kblk = keff >> 9, k = keff & 511;
  float w = Wm[(size_t)n * 512 + k];
  f16 hi = (f16)w;
  float lo = w - (float)hi;
  f16 val = (kblk < 2) ? hi : (f16)(lo * 2048.0f);
  dst[(size_t)blk * 512 + t] = val;
}

// ---------------- prep: encInP[v][j*4+g] = emb[v].Wih[g*512+j] + bih + bhh ---
__global__ __launch_bounds__(256) void prep_encin(
    const float* __restrict__ emb, const float* __restrict__ Wih,
    const float* __restrict__ bih, const float* __restrict__ bhh,
    float* __restrict__ encInP) {
  int wid = blockIdx.x * 4 + (threadIdx.x >> 6);
  int lane = threadIdx.x & 63;
  if (wid >= Vsz * 2048) return;
  int v = wid >> 11, col = wid & 2047;
  float4 e = ((const float4*)emb)[v * 64 + lane];
  float4 w = ((const float4*)Wih)[col * 64 + lane];
  float d = e.x * w.x + e.y * w.y + e.z * w.z + e.w * w.w;
  for (int off = 32; off; off >>= 1) d += __shfl_xor(d, off);
  if (lane == 0) {
    int g = col >> 9, j = col & 511;
    encInP[(size_t)v * 2048 + j * 4 + g] = d + bih[col] + bhh[col];
  }
}

// ---------------- prep: dbiasP[j*4+g] = dec_bih + dec_bhh ----------------
__global__ __launch_bounds__(256) void prep_dbias(const float* __restrict__ a,
                                                  const float* __restrict__ b,
                                                  float* __restrict__ dst) {
  int col = blockIdx.x * 256 + threadIdx.x;  // < 2048
  int g = col >> 9, j = col & 511;
  dst[j * 4 + g] = a[col] + b[col];
}

// ---------------- fused gates MFMA GEMM + LSTM cell ----------------
// fp16x3 MFMA replaces the fp32 VALU GEMM (r0-r3 showed every fp32 variant is
// operand-delivery-bound at ~60-70 TF; matrix cores broadcast operands
// internally).  Fragment-major A (h16') and B (W') make every frag load ONE
// fully-coalesced 1KB dwordx4 per wave -- no LDS, no barrier in the K-loop.
// Block: 256 thr = 4 waves (2x2), tile 128b x 128n', grid 16x16 = 256.
// Epilogue: C restaged via LDS in two half-passes (gate grouping j*4+g),
// LSTM cell math, h written back in fragment-major f16 {hi, lo, hi/2048}.
__global__ __launch_bounds__(256) void gates_mfma(
    const f16* __restrict__ Afrag,   // h16' [128 mt][48 kc][64 lane][8]
    const f16* __restrict__ Bfrag,   // W'   [128 nt][48 kc][64 lane][8]
    const float* __restrict__ addtab, const int* __restrict__ input, int tstep,
    f16* __restrict__ Aout,          // next h16', fragment-major
    float* __restrict__ cio) {       // [2048][512] f32
  __shared__ float Cst[128][68];
  const int t = threadIdx.x;
  const int lane = t & 63;
  const int wid = t >> 6;
  const int mblk = blockIdx.x >> 4;   // 0..15
  const int nblk = blockIdx.x & 15;   // 0..15

  const f16* Ab = Afrag + (((size_t)(mblk * 8 + (wid >> 1) * 4) * KC) * 64 + lane) * 8;
  const f16* Bb = Bfrag + (((size_t)(nblk * 8 + (wid & 1) * 4) * KC) * 64 + lane) * 8;

  f32x4 acc[4][4];
  {
    f32x4 z = {0.f, 0.f, 0.f, 0.f};
#pragma unroll
    for (int i = 0; i < 4; ++i)
#pragma unroll
      for (int j = 0; j < 4; ++j) acc[i][j] = z;
  }

  f16x8 pa[4], pb[4], qa[4], qb[4];

#define GLOAD(A_, B_, kc_)                                              \
  {                                                                     \
    _Pragma("unroll")                                                   \
    for (int q = 0; q < 4; ++q)                                         \
      A_[q] = *(const f16x8*)(Ab + ((size_t)q * KC + (kc_)) * 512);     \
    _Pragma("unroll")                                                   \
    for (int q = 0; q < 4; ++q)                                         \
      B_[q] = *(const f16x8*)(Bb + ((size_t)q * KC + (kc_)) * 512);     \
  }
#define GMM(A_, B_)                                                     \
  {                                                                     \
    _Pragma("unroll")                                                   \
    for (int mt = 0; mt < 4; ++mt)                                      \
      _Pragma("unroll")                                                 \
      for (int nt = 0; nt < 4; ++nt)                                    \
        acc[mt][nt] = __builtin_amdgcn_mfma_f32_16x16x32_f16(           \
            A_[mt], B_[nt], acc[mt][nt], 0, 0, 0);                      \
  }

  GLOAD(pa, pb, 0)
#pragma unroll 1
  for (int kc = 0; kc < KC; kc += 2) {
    GLOAD(qa, qb, kc + 1)
    GMM(pa, pb)
    if (kc + 2 < KC) GLOAD(pa, pb, kc + 2)
    GMM(qa, qb)
  }
#undef GLOAD
#undef GMM

  // ---- epilogue: two half-passes over n' (LDS restage 128x64 f32) ----
  const int bloc = t & 127, jg = t >> 7;
  const int bg = mblk * 128 + bloc;
  const float* arow = input
      ? addtab + (size_t)input[(size_t)bg * Ssz + tstep] * 2048
      : addtab;

#pragma unroll 1
  for (int half = 0; half < 2; ++half) {
    __syncthreads();
    if ((wid & 1) == half) {
#pragma unroll
      for (int mt = 0; mt < 4; ++mt)
#pragma unroll
        for (int nt = 0; nt < 4; ++nt)
#pragma unroll
          for (int rg = 0; rg < 4; ++rg)
            Cst[(wid >> 1) * 64 + mt * 16 + (lane >> 4) * 4 + rg]
               [nt * 16 + (lane & 15)] = acc[mt][nt][rg];
    }
    __syncthreads();

    const int j0 = nblk * 32 + half * 16 + jg * 8;   // 8 j's per thread
    float* cp = cio + (size_t)bg * 512 + j0;
    float4 cv0 = *(const float4*)(cp);
    float4 cv1 = *(const float4*)(cp + 4);
    float cin[8] = {cv0.x, cv0.y, cv0.z, cv0.w, cv1.x, cv1.y, cv1.z, cv1.w};
    float cn[8], hv[8];
#pragma unroll
    for (int jj = 0; jj < 8; ++jj) {
      float4 gq = *(const float4*)(&Cst[bloc][jg * 32 + jj * 4]);
      float4 av = *(const float4*)(arow + (size_t)(j0 + jj) * 4);
      float gi = gq.x + av.x;
      float gf = gq.y + av.y;
      float gg = gq.z + av.z;
      float go = gq.w + av.w;
      float si = 1.0f / (1.0f + expf(-gi));
      float sf = 1.0f / (1.0f + expf(-gf));
      float sg = tanhf(gg);
      float so = 1.0f / (1.0f + expf(-go));
      float c2 = sf * cin[jj] + si * sg;
      cn[jj] = c2;
      hv[jj] = so * tanhf(c2);
    }
    *(float4*)(cp)     = make_float4(cn[0], cn[1], cn[2], cn[3]);
    *(float4*)(cp + 4) = make_float4(cn[4], cn[5], cn[6], cn[7]);

    f16x8 hi8, lo8, h28;
#pragma unroll
    for (int jj = 0; jj < 8; ++jj) {
      f16 hi = (f16)hv[jj];
      hi8[jj] = hi;
      lo8[jj] = (f16)(hv[jj] - (float)hi);
      h28[jj] = (f16)((float)hi * (1.0f / 2048.0f));
    }
    const int kcH = j0 >> 5;
    const int kg = (j0 >> 3) & 3;
    size_t base = (((size_t)(bg >> 4) * KC + kcH) * 64 + kg * 16 + (bg & 15)) * 8;
    *(f16x8*)(Aout + base)                     = hi8;   // k-block 0: hi
    *(f16x8*)(Aout + base + (size_t)16 * 512)  = lo8;   // k-block 1: lo
    *(f16x8*)(Aout + base + (size_t)32 * 512)  = h28;   // k-block 2: hi/2048
  }
}

// ---------------- blend MFMA GEMM: out[b][w] = sum_k h[b][k]*Wm[w][k] --------
// 128 thr = 2 waves; block tile 64b x 32w; grid 32x8 = 256.
__global__ __launch_bounds__(128) void blend_mfma(
    const f16* __restrict__ Afrag, const f16* __restrict__ Bfrag,
    float* __restrict__ out, int rowStride) {
  const int t = threadIdx.x, lane = t & 63, wid = t >> 6;
  const int mblk = blockIdx.x >> 3;   // 0..31
  const int nblk = blockIdx.x & 7;    // 0..7
  const f16* Ab = Afrag + (((size_t)(mblk * 4 + wid * 2) * KC) * 64 + lane) * 8;
  const f16* Bb = Bfrag + (((size_t)(nblk * 2) * KC) * 64 + lane) * 8;

  f32x4 acc[2][2];
  {
    f32x4 z = {0.f, 0.f, 0.f, 0.f};
#pragma unroll
    for (int i = 0; i < 2; ++i)
#pragma unroll
      for (int j = 0; j < 2; ++j) acc[i][j] = z;
  }
  f16x8 pa[2], pb[2], qa[2], qb[2];

#define BLOAD(A_, B_, kc_)                                              \
  {                                                                     \
    _Pragma("unroll")                                                   \
    for (int q = 0; q < 2; ++q)                                         \
      A_[q] = *(const f16x8*)(Ab + ((size_t)q * KC + (kc_)) * 512);     \
    _Pragma("unroll")                                                   \
    for (int q = 0; q < 2; ++q)                                         \
      B_[q] = *(const f16x8*)(Bb + ((size_t)q * KC + (kc_)) * 512);     \
  }
#define BMM(A_, B_)                                                     \
  {                                                                     \
    _Pragma("unroll")                                                   \
    for (int mt = 0; mt < 2; ++mt)                                      \
      _Pragma("unroll")                                                 \
      for (int nt = 0; nt < 2; ++nt)                                    \
        acc[mt][nt] = __builtin_amdgcn_mfma_f32_16x16x32_f16(           \
            A_[mt], B_[nt], acc[mt][nt], 0, 0, 0);                      \
  }

  BLOAD(pa, pb, 0)
#pragma unroll 1
  for (int kc = 0; kc < KC; kc += 2) {
    BLOAD(qa, qb, kc + 1)
    BMM(pa, pb)
    if (kc + 2 < KC) BLOAD(pa, pb, kc + 2)
    BMM(qa, qb)
  }
#undef BLOAD
#undef BMM

  const int r = lane & 15, rg4 = (lane >> 4) * 4;
#pragma unroll
  for (int mt = 0; mt < 2; ++mt)
#pragma unroll
    for (int nt = 0; nt < 2; ++nt)
#pragma unroll
      for (int rg = 0; rg < 4; ++rg) {
        int b = mblk * 64 + wid * 32 + mt * 16 + rg4 + rg;
        int w = nblk * 32 + nt * 16 + r;
        out[(size_t)b * rowStride + w] = acc[mt][nt][rg];
      }
}

// ---------------- decoder c0 = last encoder h (reconstruct hi+lo) ------------
__global__ __launch_bounds__(256) void dec_cinit(const f16* __restrict__ hE,
                                                 float* __restrict__ cD) {
  int idx = blockIdx.x * 256 + threadIdx.x;  // < 2048*512
  int b = idx >> 9, j = idx & 511;
  size_t base = (((size_t)(b >> 4) * KC + (j >> 5)) * 64
                 + ((j >> 3) & 3) * 16 + (b & 15)) * 8 + (j & 7);
  cD[idx] = (float)hE[base] + (float)hE[base + (size_t)16 * 512];
}

// ---------------- scores + log_softmax + gumbel sample + mask ----------------
__global__ __launch_bounds__(256) void scores_sample(
    const float* __restrict__ b1, const float* __restrict__ b2,
    const float* __restrict__ vt, unsigned long long* __restrict__ mask,
    float* __restrict__ probs, float* __restrict__ tour,
    int stepk, unsigned kA, unsigned kB) {
  __shared__ float b2s[256];
  __shared__ float vts[256];
  __shared__ float sc[52];
  const int t = threadIdx.x, b = blockIdx.x;
  b2s[t] = b2[(size_t)b * Wsz + t];
  vts[t] = vt[t];
  __syncthreads();
  const int wave = t >> 6, lane = t & 63;
  for (int s = wave; s < Ssz; s += 4) {
    const float* row = b1 + ((size_t)b * Ssz + s) * Wsz;
    float v = 0.f;
#pragma unroll
    for (int q = 0; q < 4; ++q) {
      int w = lane + 64 * q;
      v += vts[w] * tanhf(row[w] + b2s[w]);
    }
    for (int off = 32; off; off >>= 1) v += __shfl_xor(v, off);
    if (lane == 0) sc[s] = v;
  }
  __syncthreads();
  if (wave == 0) {
    unsigned long long m = mask[b];
    float x = (lane < Ssz) ? sc[lane] : -INFINITY;
    if (lane < Ssz && ((m >> lane) & 1ull)) x = -100000.0f;
    float mv = x;
    for (int off = 32; off; off >>= 1) mv = fmaxf(mv, __shfl_xor(mv, off));
    float sh = x - mv;
    float e = (lane < Ssz) ? expf(sh) : 0.f;
    float ssum = e;
    for (int off = 32; off; off >>= 1) ssum += __shfl_xor(ssum, off);
    float lg = logf(ssum);
    float logp = sh - lg;
    if (lane < Ssz) probs[(size_t)b * (Lsz * Ssz) + stepk * Ssz + lane] = logp;

    float val = -INFINITY;
    if (lane < Ssz) {
      unsigned j = (unsigned)(b * Ssz + lane);
      unsigned o0, o1, bits;
#if JAX_THREEFRY_PARTITIONABLE
      threefry2x32_hd(kA, kB, 0u, j, o0, o1);
      bits = o0 ^ o1;
#else
      if (j < 51200u) { threefry2x32_hd(kA, kB, j, j + 51200u, o0, o1); bits = o0; }
      else           { threefry2x32_hd(kA, kB, j - 51200u, j, o0, o1); bits = o1; }
#endif
      float f = __uint_as_float((bits >> 9) | 0x3F800000u) - 1.0f;
      float u = fmaxf(1.17549435e-38f, f + 1.17549435e-38f);
      val = logp - logf(-logf(u));
    }
    int idx = lane;
    for (int off = 32; off; off >>= 1) {
      float ov = __shfl_xor(val, off);
      int oi = __shfl_xor(idx, off);
      if (ov > val || (ov == val && oi < idx)) { val = ov; idx = oi; }
    }
    if (lane == 0) {
      tour[(size_t)b * Lsz + stepk] = (float)idx;
      mask[b] = m | (1ull << idx);
    }
  }
}

extern "C" void kernel_launch(void* const* d_in, const int* in_sizes, int n_in,
                              void* d_out, int out_size, void* d_ws, size_t ws_size,
                              hipStream_t stream) {
  (void)in_sizes; (void)n_in; (void)out_size; (void)ws_size;
  const int*   input = (const int*)d_in[0];
  const float* emb   = (const float*)d_in[1];
  const float* eWih  = (const float*)d_in[2];
  const float* eWhh  = (const float*)d_in[3];
  const float* ebih  = (const float*)d_in[4];
  const float* ebhh  = (const float*)d_in[5];
  /* d_in[6] dec_Wih unused: decoder input is always zero */
  const float* dWhh  = (const float*)d_in[7];
  const float* dbih  = (const float*)d_in[8];
  const float* dbhh  = (const float*)d_in[9];
  const float* W1    = (const float*)d_in[10];
  const float* W2    = (const float*)d_in[11];
  const float* vt    = (const float*)d_in[12];
  float* outF = (float*)d_out;

  float* wsf = (float*)d_ws;
  size_t o = 0;
  const size_t GFRAG = (size_t)128 * KC * 512;  // f16 count = 3,145,728 (6MB)
  const size_t BFRAG = (size_t)16 * KC * 512;   // f16 count = 393,216
  f16* BfE = (f16*)(wsf + o); o += GFRAG / 2;   // enc gates W frag pack
  f16* BfD = (f16*)(wsf + o); o += GFRAG / 2;   // dec gates W frag pack
  f16* Bb1 = (f16*)(wsf + o); o += BFRAG / 2;   // W1 blend frag pack
  f16* Bb2 = (f16*)(wsf + o); o += BFRAG / 2;   // W2 blend frag pack
  float* encInP = wsf + o; o += (size_t)Vsz * 2048;
  float* dbiasP = wsf + o; o += 2048;
  f16* hEA = (f16*)(wsf + o); o += GFRAG / 2;   // encoder h16' dbuf
  f16* hEB = (f16*)(wsf + o); o += GFRAG / 2;
  f16* hDA = (f16*)(wsf + o); o += GFRAG / 2;   // decoder h16' dbuf
  f16* hDB = (f16*)(wsf + o); o += GFRAG / 2;
  float* cE  = wsf + o; o += (size_t)Bsz * Hsz;  // enc c, reused as dec c
  float* b2  = wsf + o; o += (size_t)Bsz * Wsz;
  float* b1  = wsf + o; o += (size_t)Bsz * Ssz * Wsz;
  unsigned long long* maskp = (unsigned long long*)(wsf + o); o += Bsz * 2;

  hipMemsetAsync(hEA, 0, GFRAG * 2, stream);
  hipMemsetAsync(hDA, 0, GFRAG * 2, stream);
  hipMemsetAsync(cE, 0, (size_t)Bsz * Hsz * 4, stream);
  hipMemsetAsync(maskp, 0, (size_t)Bsz * 8, stream);

  prep_gfrag<<<128 * KC, 512, 0, stream>>>(eWhh, BfE);
  prep_gfrag<<<128 * KC, 512, 0, stream>>>(dWhh, BfD);
  prep_bfrag<<<16 * KC, 512, 0, stream>>>(W1, Bb1);
  prep_bfrag<<<16 * KC, 512, 0, stream>>>(W2, Bb2);
  prep_encin<<<(Vsz * 2048) / 4, 256, 0, stream>>>(emb, eWih, ebih, ebhh, encInP);
  prep_dbias<<<8, 256, 0, stream>>>(dbih, dbhh, dbiasP);

  // host-side: step keys = jax.random.split(jax.random.key(42), 50)
  unsigned kAh[Lsz], kBh[Lsz];
  for (int k = 0; k < Lsz; ++k) {
#if JAX_THREEFRY_PARTITIONABLE
    threefry2x32_hd(0u, 42u, 0u, (unsigned)k, kAh[k], kBh[k]);
#else
    unsigned a0, a1, c0, c1;
    if (k < 25) {
      threefry2x32_hd(0u, 42u, 2u * k,      2u * k + 50u, a0, a1); kAh[k] = a0;
      threefry2x32_hd(0u, 42u, 2u * k + 1u, 2u * k + 51u, c0, c1); kBh[k] = c0;
    } else {
      threefry2x32_hd(0u, 42u, 2u * k - 50u, 2u * k,      a0, a1); kAh[k] = a1;
      threefry2x32_hd(0u, 42u, 2u * k - 49u, 2u * k + 1u, c0, c1); kBh[k] = c1;
    }
#endif
  }

  // encoder
  f16* hr = hEA; f16* hw = hEB;
  for (int t = 0; t < Ssz; ++t) {
    gates_mfma<<<256, 256, 0, stream>>>(hr, BfE, encInP, input, t, hw, cE);
    blend_mfma<<<256, 128, 0, stream>>>(hw, Bb1, b1 + (size_t)t * Wsz, Ssz * Wsz);
    f16* tp = hr; hr = hw; hw = tp;
  }
  // decoder init: c0 = last encoder h (hi+lo reconstruct), h0 = 0, mask = 0
  dec_cinit<<<(Bsz * Hsz) / 256, 256, 0, stream>>>(hr, cE);

  f16* dr = hDA; f16* dw = hDB;
  for (int k = 0; k < Lsz; ++k) {
    gates_mfma<<<256, 256, 0, stream>>>(dr, BfD, dbiasP, nullptr, 0, dw, cE);
    blend_mfma<<<256, 128, 0, stream>>>(dw, Bb2, b2, Wsz);
    scores_sample<<<Bsz, 256, 0, stream>>>(b1, b2, vt, maskp, outF,
                                           outF + (size_t)Bsz * Lsz * Ssz,
                                           k, kAh[k], kBh[k]);
    f16* tp = dr; dr = dw; dw = tp;
  }
}

// Round 5
// 5809.174 us; speedup vs baseline: 2.7397x; 1.0146x over previous
//
#include <hip/hip_runtime.h>
#include <cstdint>

// Problem constants
#define Bsz 2048
#define Ssz 50
#define Esz 256
#define Hsz 512
#define Wsz 256
#define Lsz 50
#define Vsz 51
#define KC 48   // k-chunks of 32 over K_eff = 1536 (fp16x3 split)

// JAX RNG semantics: 1 = threefry_partitionable (jax >= 0.4.36 default), 0 = original
#define JAX_THREEFRY_PARTITIONABLE 1

typedef _Float16 f16;
typedef _Float16 f16x8 __attribute__((ext_vector_type(8)));
typedef float f32x4 __attribute__((ext_vector_type(4)));

// ---------------- threefry2x32 (20 rounds), key words (k0,k1) ----------------
__host__ __device__ __forceinline__ void threefry2x32_hd(
    unsigned k0, unsigned k1, unsigned x0, unsigned x1,
    unsigned& o0, unsigned& o1) {
  unsigned ks2 = k0 ^ k1 ^ 0x1BD11BDAu;
  x0 += k0; x1 += k1;
#define TF_RND(r) { x0 += x1; x1 = (x1 << (r)) | (x1 >> (32 - (r))); x1 ^= x0; }
  TF_RND(13) TF_RND(15) TF_RND(26) TF_RND(6)
  x0 += k1; x1 += ks2 + 1u;
  TF_RND(17) TF_RND(29) TF_RND(16) TF_RND(24)
  x0 += ks2; x1 += k0 + 2u;
  TF_RND(13) TF_RND(15) TF_RND(26) TF_RND(6)
  x0 += k0; x1 += k1 + 3u;
  TF_RND(17) TF_RND(29) TF_RND(16) TF_RND(24)
  x0 += k1; x1 += ks2 + 4u;
  TF_RND(13) TF_RND(15) TF_RND(26) TF_RND(6)
  x0 += ks2; x1 += k0 + 5u;
#undef TF_RND
  o0 = x0; o1 = x1;
}

// ---- prep: gates W fragment pack ----
// B' layout: [ntile 0..127][kc 0..47][lane 0..63][e 0..7] f16, where the
// mfma_f32_16x16x32_f16 B-frag for (ntile,kc) has lane l = kg*16 + c holding
// Wf16[n = ntile*16 + c][k = kc*32 + kg*8 + e].  n' = j*4+g (gate-interleaved),
// Wf16 k-blocks = [Whi | Whi | Wlo*2048] (fp16x3; third term rescaled so the
// lo-part stays in fp16 normal range -> immune to MFMA denorm flush).
__global__ __launch_bounds__(512) void prep_gfrag(const float* __restrict__ Whh,
                                                  f16* __restrict__ dst) {
  int blk = blockIdx.x;            // ntile*48 + kc   (grid 128*48 = 6144)
  int ntile = blk / KC, kc = blk % KC;
  int t = threadIdx.x;             // 512 = l*8 + e
  int l = t >> 3, e = t & 7;
  int c = l & 15, kg = l >> 4;
  int n = ntile * 16 + c;          // n' in [0,2048)
  int keff = kc * 32 + kg * 8 + e;
  int kblk = keff >> 9, k = keff & 511;
  int j = n >> 2, g = n & 3;
  float w = Whh[(size_t)(g * 512 + j) * 512 + k];
  f16 hi = (f16)w;
  float lo = w - (float)hi;
  f16 val = (kblk < 2) ? hi : (f16)(lo * 2048.0f);
  dst[(size_t)blk * 512 + t] = val;
}

// ---- prep: blend W fragment pack: [wtile 0..15][kc][lane][e], n = w direct --
__global__ __launch_bounds__(512) void prep_bfrag(const float* __restrict__ Wm,
                                                  f16* __restrict__ dst) {
  int blk = blockIdx.x;            // wtile*48 + kc   (grid 16*48 = 768)
  int wtile = blk / KC, kc = blk % KC;
  int t = threadIdx.x;
  int l = t >> 3, e = t & 7;
  int c = l & 15, kg = l >> 4;
  int n = wtile * 16 + c;          // w in [0,256)
  int keff = kc * 32 + kg * 8 + e;
  int kblk = keff >> 9, k = keff & 511;
  float w = Wm[(size_t)n * 512 + k];
  f16 hi = (f16)w;
  float lo = w - (float)hi;
  f16 val = (kblk < 2) ? hi : (f16)(lo * 2048.0f);
  dst[(size_t)blk * 512 + t] = val;
}

// ---------------- prep: encInP[v][j*4+g] = emb[v].Wih[g*512+j] + bih + bhh ---
__global__ __launch_bounds__(256) void prep_encin(
    const float* __restrict__ emb, const float* __restrict__ Wih,
    const float* __restrict__ bih, const float* __restrict__ bhh,
    float* __restrict__ encInP) {
  int wid = blockIdx.x * 4 + (threadIdx.x >> 6);
  int lane = threadIdx.x & 63;
  if (wid >= Vsz * 2048) return;
  int v = wid >> 11, col = wid & 2047;
  float4 e = ((const float4*)emb)[v * 64 + lane];
  float4 w = ((const float4*)Wih)[col * 64 + lane];
  float d = e.x * w.x + e.y * w.y + e.z * w.z + e.w * w.w;
  for (int off = 32; off; off >>= 1) d += __shfl_xor(d, off);
  if (lane == 0) {
    int g = col >> 9, j = col & 511;
    encInP[(size_t)v * 2048 + j * 4 + g] = d + bih[col] + bhh[col];
  }
}

// ---------------- prep: dbiasP[j*4+g] = dec_bih + dec_bhh ----------------
__global__ __launch_bounds__(256) void prep_dbias(const float* __restrict__ a,
                                                  const float* __restrict__ b,
                                                  float* __restrict__ dst) {
  int col = blockIdx.x * 256 + threadIdx.x;  // < 2048
  int g = col >> 9, j = col & 511;
  dst[j * 4 + g] = a[col] + b[col];
}

// ---------------- fused gates MFMA GEMM + LSTM cell ----------------
// fp16x3 MFMA; fragment-major A/B (1KB coalesced frag loads, no LDS/barrier
// in K-loop).  Block: 256 thr = 4 waves (2x2), tile 128b x 128n'.
// XCD-aware swizzle (T1): grid 256 = 1 block/CU; bid&7 = XCD (round-robin
// dispatch), so XCD x owns mblks {2x,2x+1} x all 16 nblks -> per-XCD A-slice
// = 1.5MB (L2-resident), B streamed once per XCD from L3 (~60MB/dispatch
// total vs ~400MB thrashed before).  Mapping is self-consistent across
// dispatches: XCD x writes h-rows [256x,256x+256) and reads the same rows
// next step -> producer-consumer L2 reuse.
__global__ __launch_bounds__(256) void gates_mfma(
    const f16* __restrict__ Afrag,   // h16' [128 mt][48 kc][64 lane][8]
    const f16* __restrict__ Bfrag,   // W'   [128 nt][48 kc][64 lane][8]
    const float* __restrict__ addtab, const int* __restrict__ input, int tstep,
    f16* __restrict__ Aout,          // next h16', fragment-major
    float* __restrict__ cio) {       // [2048][512] f32
  __shared__ float Cst[128][68];
  const int t = threadIdx.x;
  const int lane = t & 63;
  const int wid = t >> 6;
  const int bid = blockIdx.x;
  const int xcd = bid & 7, loc = bid >> 3;          // loc in [0,32)
  const int mblk = xcd * 2 + (loc >> 4);            // 0..15
  const int nblk = loc & 15;                        // 0..15

  const f16* Ab = Afrag + (((size_t)(mblk * 8 + (wid >> 1) * 4) * KC) * 64 + lane) * 8;
  const f16* Bb = Bfrag + (((size_t)(nblk * 8 + (wid & 1) * 4) * KC) * 64 + lane) * 8;

  f32x4 acc[4][4];
  {
    f32x4 z = {0.f, 0.f, 0.f, 0.f};
#pragma unroll
    for (int i = 0; i < 4; ++i)
#pragma unroll
      for (int j = 0; j < 4; ++j) acc[i][j] = z;
  }

  f16x8 pa[4], pb[4], qa[4], qb[4];

#define GLOAD(A_, B_, kc_)                                              \
  {                                                                     \
    _Pragma("unroll")                                                   \
    for (int q = 0; q < 4; ++q)                                         \
      A_[q] = *(const f16x8*)(Ab + ((size_t)q * KC + (kc_)) * 512);     \
    _Pragma("unroll")                                                   \
    for (int q = 0; q < 4; ++q)                                         \
      B_[q] = *(const f16x8*)(Bb + ((size_t)q * KC + (kc_)) * 512);     \
  }
#define GMM(A_, B_)                                                     \
  {                                                                     \
    _Pragma("unroll")                                                   \
    for (int mt = 0; mt < 4; ++mt)                                      \
      _Pragma("unroll")                                                 \
      for (int nt = 0; nt < 4; ++nt)                                    \
        acc[mt][nt] = __builtin_amdgcn_mfma_f32_16x16x32_f16(           \
            A_[mt], B_[nt], acc[mt][nt], 0, 0, 0);                      \
  }

  GLOAD(pa, pb, 0)
#pragma unroll 1
  for (int kc = 0; kc < KC; kc += 2) {
    GLOAD(qa, qb, kc + 1)
    GMM(pa, pb)
    if (kc + 2 < KC) GLOAD(pa, pb, kc + 2)
    GMM(qa, qb)
  }
#undef GLOAD
#undef GMM

  // ---- epilogue: two half-passes over n' (LDS restage 128x64 f32) ----
  const int bloc = t & 127, jg = t >> 7;
  const int bg = mblk * 128 + bloc;
  const float* arow = input
      ? addtab + (size_t)input[(size_t)bg * Ssz + tstep] * 2048
      : addtab;

#pragma unroll 1
  for (int half = 0; half < 2; ++half) {
    __syncthreads();
    if ((wid & 1) == half) {
#pragma unroll
      for (int mt = 0; mt < 4; ++mt)
#pragma unroll
        for (int nt = 0; nt < 4; ++nt)
#pragma unroll
          for (int rg = 0; rg < 4; ++rg)
            Cst[(wid >> 1) * 64 + mt * 16 + (lane >> 4) * 4 + rg]
               [nt * 16 + (lane & 15)] = acc[mt][nt][rg];
    }
    __syncthreads();

    const int j0 = nblk * 32 + half * 16 + jg * 8;   // 8 j's per thread
    float* cp = cio + (size_t)bg * 512 + j0;
    float4 cv0 = *(const float4*)(cp);
    float4 cv1 = *(const float4*)(cp + 4);
    float cin[8] = {cv0.x, cv0.y, cv0.z, cv0.w, cv1.x, cv1.y, cv1.z, cv1.w};
    float cn[8], hv[8];
#pragma unroll
    for (int jj = 0; jj < 8; ++jj) {
      float4 gq = *(const float4*)(&Cst[bloc][jg * 32 + jj * 4]);
      float4 av = *(const float4*)(arow + (size_t)(j0 + jj) * 4);
      float gi = gq.x + av.x;
      float gf = gq.y + av.y;
      float gg = gq.z + av.z;
      float go = gq.w + av.w;
      float si = 1.0f / (1.0f + expf(-gi));
      float sf = 1.0f / (1.0f + expf(-gf));
      float sg = tanhf(gg);
      float so = 1.0f / (1.0f + expf(-go));
      float c2 = sf * cin[jj] + si * sg;
      cn[jj] = c2;
      hv[jj] = so * tanhf(c2);
    }
    *(float4*)(cp)     = make_float4(cn[0], cn[1], cn[2], cn[3]);
    *(float4*)(cp + 4) = make_float4(cn[4], cn[5], cn[6], cn[7]);

    f16x8 hi8, lo8, h28;
#pragma unroll
    for (int jj = 0; jj < 8; ++jj) {
      f16 hi = (f16)hv[jj];
      hi8[jj] = hi;
      lo8[jj] = (f16)(hv[jj] - (float)hi);
      h28[jj] = (f16)((float)hi * (1.0f / 2048.0f));
    }
    const int kcH = j0 >> 5;
    const int kg = (j0 >> 3) & 3;
    size_t base = (((size_t)(bg >> 4) * KC + kcH) * 64 + kg * 16 + (bg & 15)) * 8;
    *(f16x8*)(Aout + base)                     = hi8;   // k-block 0: hi
    *(f16x8*)(Aout + base + (size_t)16 * 512)  = lo8;   // k-block 1: lo
    *(f16x8*)(Aout + base + (size_t)32 * 512)  = h28;   // k-block 2: hi/2048
  }
}

// ---------------- blend MFMA GEMM: out[b][w] = sum_k h[b][k]*Wm[w][k] --------
// 128 thr = 2 waves; block tile 64b x 32w; grid 256.  XCD swizzle aligned
// with gates_mfma: XCD x covers b-rows [256x, 256x+256) -> reads the h-frags
// its own XCD's gates dispatch just wrote (L2 dirty-line reuse); A-slice
// 768KB + B 768KB both L2-resident per XCD.
__global__ __launch_bounds__(128) void blend_mfma(
    const f16* __restrict__ Afrag, const f16* __restrict__ Bfrag,
    float* __restrict__ out, int rowStride) {
  const int t = threadIdx.x, lane = t & 63, wid = t >> 6;
  const int bid = blockIdx.x;
  const int xcd = bid & 7, loc = bid >> 3;          // loc in [0,32)
  const int mblk = xcd * 4 + (loc >> 3);            // 0..31
  const int nblk = loc & 7;                         // 0..7
  const f16* Ab = Afrag + (((size_t)(mblk * 4 + wid * 2) * KC) * 64 + lane) * 8;
  const f16* Bb = Bfrag + (((size_t)(nblk * 2) * KC) * 64 + lane) * 8;

  f32x4 acc[2][2];
  {
    f32x4 z = {0.f, 0.f, 0.f, 0.f};
#pragma unroll
    for (int i = 0; i < 2; ++i)
#pragma unroll
      for (int j = 0; j < 2; ++j) acc[i][j] = z;
  }
  f16x8 pa[2], pb[2], qa[2], qb[2];

#define BLOAD(A_, B_, kc_)                                              \
  {                                                                     \
    _Pragma("unroll")                                                   \
    for (int q = 0; q < 2; ++q)                                         \
      A_[q] = *(const f16x8*)(Ab + ((size_t)q * KC + (kc_)) * 512);     \
    _Pragma("unroll")                                                   \
    for (int q = 0; q < 2; ++q)                                         \
      B_[q] = *(const f16x8*)(Bb + ((size_t)q * KC + (kc_)) * 512);     \
  }
#define BMM(A_, B_)                                                     \
  {                                                                     \
    _Pragma("unroll")                                                   \
    for (int mt = 0; mt < 2; ++mt)                                      \
      _Pragma("unroll")                                                 \
      for (int nt = 0; nt < 2; ++nt)                                    \
        acc[mt][nt] = __builtin_amdgcn_mfma_f32_16x16x32_f16(           \
            A_[mt], B_[nt], acc[mt][nt], 0, 0, 0);                      \
  }

  BLOAD(pa, pb, 0)
#pragma unroll 1
  for (int kc = 0; kc < KC; kc += 2) {
    BLOAD(qa, qb, kc + 1)
    BMM(pa, pb)
    if (kc + 2 < KC) BLOAD(pa, pb, kc + 2)
    BMM(qa, qb)
  }
#undef BLOAD
#undef BMM

  const int r = lane & 15, rg4 = (lane >> 4) * 4;
#pragma unroll
  for (int mt = 0; mt < 2; ++mt)
#pragma unroll
    for (int nt = 0; nt < 2; ++nt)
#pragma unroll
      for (int rg = 0; rg < 4; ++rg) {
        int b = mblk * 64 + wid * 32 + mt * 16 + rg4 + rg;
        int w = nblk * 32 + nt * 16 + r;
        out[(size_t)b * rowStride + w] = acc[mt][nt][rg];
      }
}

// ---------------- decoder c0 = last encoder h (reconstruct hi+lo) ------------
__global__ __launch_bounds__(256) void dec_cinit(const f16* __restrict__ hE,
                                                 float* __restrict__ cD) {
  int idx = blockIdx.x * 256 + threadIdx.x;  // < 2048*512
  int b = idx >> 9, j = idx & 511;
  size_t base = (((size_t)(b >> 4) * KC + (j >> 5)) * 64
                 + ((j >> 3) & 3) * 16 + (b & 15)) * 8 + (j & 7);
  cD[idx] = (float)hE[base] + (float)hE[base + (size_t)16 * 512];
}

// ---------------- scores + log_softmax + gumbel sample + mask ----------------
__global__ __launch_bounds__(256) void scores_sample(
    const float* __restrict__ b1, const float* __restrict__ b2,
    const float* __restrict__ vt, unsigned long long* __restrict__ mask,
    float* __restrict__ probs, float* __restrict__ tour,
    int stepk, unsigned kA, unsigned kB) {
  __shared__ float b2s[256];
  __shared__ float vts[256];
  __shared__ float sc[52];
  const int t = threadIdx.x, b = blockIdx.x;
  b2s[t] = b2[(size_t)b * Wsz + t];
  vts[t] = vt[t];
  __syncthreads();
  const int wave = t >> 6, lane = t & 63;
  for (int s = wave; s < Ssz; s += 4) {
    const float* row = b1 + ((size_t)b * Ssz + s) * Wsz;
    float v = 0.f;
#pragma unroll
    for (int q = 0; q < 4; ++q) {
      int w = lane + 64 * q;
      v += vts[w] * tanhf(row[w] + b2s[w]);
    }
    for (int off = 32; off; off >>= 1) v += __shfl_xor(v, off);
    if (lane == 0) sc[s] = v;
  }
  __syncthreads();
  if (wave == 0) {
    unsigned long long m = mask[b];
    float x = (lane < Ssz) ? sc[lane] : -INFINITY;
    if (lane < Ssz && ((m >> lane) & 1ull)) x = -100000.0f;
    float mv = x;
    for (int off = 32; off; off >>= 1) mv = fmaxf(mv, __shfl_xor(mv, off));
    float sh = x - mv;
    float e = (lane < Ssz) ? expf(sh) : 0.f;
    float ssum = e;
    for (int off = 32; off; off >>= 1) ssum += __shfl_xor(ssum, off);
    float lg = logf(ssum);
    float logp = sh - lg;
    if (lane < Ssz) probs[(size_t)b * (Lsz * Ssz) + stepk * Ssz + lane] = logp;

    float val = -INFINITY;
    if (lane < Ssz) {
      unsigned j = (unsigned)(b * Ssz + lane);
      unsigned o0, o1, bits;
#if JAX_THREEFRY_PARTITIONABLE
      threefry2x32_hd(kA, kB, 0u, j, o0, o1);
      bits = o0 ^ o1;
#else
      if (j < 51200u) { threefry2x32_hd(kA, kB, j, j + 51200u, o0, o1); bits = o0; }
      else           { threefry2x32_hd(kA, kB, j - 51200u, j, o0, o1); bits = o1; }
#endif
      float f = __uint_as_float((bits >> 9) | 0x3F800000u) - 1.0f;
      float u = fmaxf(1.17549435e-38f, f + 1.17549435e-38f);
      val = logp - logf(-logf(u));
    }
    int idx = lane;
    for (int off = 32; off; off >>= 1) {
      float ov = __shfl_xor(val, off);
      int oi = __shfl_xor(idx, off);
      if (ov > val || (ov == val && oi < idx)) { val = ov; idx = oi; }
    }
    if (lane == 0) {
      tour[(size_t)b * Lsz + stepk] = (float)idx;
      mask[b] = m | (1ull << idx);
    }
  }
}

extern "C" void kernel_launch(void* const* d_in, const int* in_sizes, int n_in,
                              void* d_out, int out_size, void* d_ws, size_t ws_size,
                              hipStream_t stream) {
  (void)in_sizes; (void)n_in; (void)out_size; (void)ws_size;
  const int*   input = (const int*)d_in[0];
  const float* emb   = (const float*)d_in[1];
  const float* eWih  = (const float*)d_in[2];
  const float* eWhh  = (const float*)d_in[3];
  const float* ebih  = (const float*)d_in[4];
  const float* ebhh  = (const float*)d_in[5];
  /* d_in[6] dec_Wih unused: decoder input is always zero */
  const float* dWhh  = (const float*)d_in[7];
  const float* dbih  = (const float*)d_in[8];
  const float* dbhh  = (const float*)d_in[9];
  const float* W1    = (const float*)d_in[10];
  const float* W2    = (const float*)d_in[11];
  const float* vt    = (const float*)d_in[12];
  float* outF = (float*)d_out;

  float* wsf = (float*)d_ws;
  size_t o = 0;
  const size_t GFRAG = (size_t)128 * KC * 512;  // f16 count = 3,145,728 (6MB)
  const size_t BFRAG = (size_t)16 * KC * 512;   // f16 count = 393,216
  f16* BfE = (f16*)(wsf + o); o += GFRAG / 2;   // enc gates W frag pack
  f16* BfD = (f16*)(wsf + o); o += GFRAG / 2;   // dec gates W frag pack
  f16* Bb1 = (f16*)(wsf + o); o += BFRAG / 2;   // W1 blend frag pack
  f16* Bb2 = (f16*)(wsf + o); o += BFRAG / 2;   // W2 blend frag pack
  float* encInP = wsf + o; o += (size_t)Vsz * 2048;
  float* dbiasP = wsf + o; o += 2048;
  f16* hEA = (f16*)(wsf + o); o += GFRAG / 2;   // encoder h16' dbuf
  f16* hEB = (f16*)(wsf + o); o += GFRAG / 2;
  f16* hDA = (f16*)(wsf + o); o += GFRAG / 2;   // decoder h16' dbuf
  f16* hDB = (f16*)(wsf + o); o += GFRAG / 2;
  float* cE  = wsf + o; o += (size_t)Bsz * Hsz;  // enc c, reused as dec c
  float* b2  = wsf + o; o += (size_t)Bsz * Wsz;
  float* b1  = wsf + o; o += (size_t)Bsz * Ssz * Wsz;
  unsigned long long* maskp = (unsigned long long*)(wsf + o); o += Bsz * 2;

  hipMemsetAsync(hEA, 0, GFRAG * 2, stream);
  hipMemsetAsync(hDA, 0, GFRAG * 2, stream);
  hipMemsetAsync(cE, 0, (size_t)Bsz * Hsz * 4, stream);
  hipMemsetAsync(maskp, 0, (size_t)Bsz * 8, stream);

  prep_gfrag<<<128 * KC, 512, 0, stream>>>(eWhh, BfE);
  prep_gfrag<<<128 * KC, 512, 0, stream>>>(dWhh, BfD);
  prep_bfrag<<<16 * KC, 512, 0, stream>>>(W1, Bb1);
  prep_bfrag<<<16 * KC, 512, 0, stream>>>(W2, Bb2);
  prep_encin<<<(Vsz * 2048) / 4, 256, 0, stream>>>(emb, eWih, ebih, ebhh, encInP);
  prep_dbias<<<8, 256, 0, stream>>>(dbih, dbhh, dbiasP);

  // host-side: step keys = jax.random.split(jax.random.key(42), 50)
  unsigned kAh[Lsz], kBh[Lsz];
  for (int k = 0; k < Lsz; ++k) {
#if JAX_THREEFRY_PARTITIONABLE
    threefry2x32_hd(0u, 42u, 0u, (unsigned)k, kAh[k], kBh[k]);
#else
    unsigned a0, a1, c0, c1;
    if (k < 25) {
      threefry2x32_hd(0u, 42u, 2u * k,      2u * k + 50u, a0, a1); kAh[k] = a0;
      threefry2x32_hd(0u, 42u, 2u * k + 1u, 2u * k + 51u, c0, c1); kBh[k] = c0;
    } else {
      threefry2x32_hd(0u, 42u, 2u * k - 50u, 2u * k,      a0, a1); kAh[k] = a1;
      threefry2x32_hd(0u, 42u, 2u * k - 49u, 2u * k + 1u, c0, c1); kBh[k] = c1;
    }
#endif
  }

  // encoder
  f16* hr = hEA; f16* hw = hEB;
  for (int t = 0; t < Ssz; ++t) {
    gates_mfma<<<256, 256, 0, stream>>>(hr, BfE, encInP, input, t, hw, cE);
    blend_mfma<<<256, 128, 0, stream>>>(hw, Bb1, b1 + (size_t)t * Wsz, Ssz * Wsz);
    f16* tp = hr; hr = hw; hw = tp;
  }
  // decoder init: c0 = last encoder h (hi+lo reconstruct), h0 = 0, mask = 0
  dec_cinit<<<(Bsz * Hsz) / 256, 256, 0, stream>>>(hr, cE);

  f16* dr = hDA; f16* dw = hDB;
  for (int k = 0; k < Lsz; ++k) {
    gates_mfma<<<256, 256, 0, stream>>>(dr, BfD, dbiasP, nullptr, 0, dw, cE);
    blend_mfma<<<256, 128, 0, stream>>>(dw, Bb2, b2, Wsz);
    scores_sample<<<Bsz, 256, 0, stream>>>(b1, b2, vt, maskp, outF,
                                           outF + (size_t)Bsz * Lsz * Ssz,
                                           k, kAh[k], kBh[k]);
    f16* tp = dr; dr = dw; dw = tp;
  }
}

// Round 6
// 5232.484 us; speedup vs baseline: 3.0416x; 1.1102x over previous
//
#include <hip/hip_runtime.h>
#include <cstdint>

// Problem constants
#define Bsz 2048
#define Ssz 50
#define Esz 256
#define Hsz 512
#define Wsz 256
#define Lsz 50
#define Vsz 51
#define KC 48   // k-chunks of 32 over K_eff = 1536 (fp16x3 split)

// JAX RNG semantics: 1 = threefry_partitionable (jax >= 0.4.36 default), 0 = original
#define JAX_THREEFRY_PARTITIONABLE 1

typedef _Float16 f16;
typedef _Float16 f16x8 __attribute__((ext_vector_type(8)));
typedef float f32x4 __attribute__((ext_vector_type(4)));

// ---------------- threefry2x32 (20 rounds), key words (k0,k1) ----------------
__host__ __device__ __forceinline__ void threefry2x32_hd(
    unsigned k0, unsigned k1, unsigned x0, unsigned x1,
    unsigned& o0, unsigned& o1) {
  unsigned ks2 = k0 ^ k1 ^ 0x1BD11BDAu;
  x0 += k0; x1 += k1;
#define TF_RND(r) { x0 += x1; x1 = (x1 << (r)) | (x1 >> (32 - (r))); x1 ^= x0; }
  TF_RND(13) TF_RND(15) TF_RND(26) TF_RND(6)
  x0 += k1; x1 += ks2 + 1u;
  TF_RND(17) TF_RND(29) TF_RND(16) TF_RND(24)
  x0 += ks2; x1 += k0 + 2u;
  TF_RND(13) TF_RND(15) TF_RND(26) TF_RND(6)
  x0 += k0; x1 += k1 + 3u;
  TF_RND(17) TF_RND(29) TF_RND(16) TF_RND(24)
  x0 += k1; x1 += ks2 + 4u;
  TF_RND(13) TF_RND(15) TF_RND(26) TF_RND(6)
  x0 += ks2; x1 += k0 + 5u;
#undef TF_RND
  o0 = x0; o1 = x1;
}

// ---- prep: gates W fragment pack ----
// B' layout: [ntile 0..127][kc 0..47][lane 0..63][e 0..7] f16, where the
// mfma_f32_16x16x32_f16 B-frag for (ntile,kc) has lane l = kg*16 + c holding
// Wf16[n = ntile*16 + c][k = kc*32 + kg*8 + e].  n' = j*4+g (gate-interleaved),
// Wf16 k-blocks = [Whi | Whi | Wlo*2048] (fp16x3; third term rescaled so the
// lo-part stays in fp16 normal range -> immune to MFMA denorm flush).
__global__ __launch_bounds__(512) void prep_gfrag(const float* __restrict__ Whh,
                                                  f16* __restrict__ dst) {
  int blk = blockIdx.x;            // ntile*48 + kc   (grid 128*48 = 6144)
  int ntile = blk / KC, kc = blk % KC;
  int t = threadIdx.x;             // 512 = l*8 + e
  int l = t >> 3, e = t & 7;
  int c = l & 15, kg = l >> 4;
  int n = ntile * 16 + c;          // n' in [0,2048)
  int keff = kc * 32 + kg * 8 + e;
  int kblk = keff >> 9, k = keff & 511;
  int j = n >> 2, g = n & 3;
  float w = Whh[(size_t)(g * 512 + j) * 512 + k];
  f16 hi = (f16)w;
  float lo = w - (float)hi;
  f16 val = (kblk < 2) ? hi : (f16)(lo * 2048.0f);
  dst[(size_t)blk * 512 + t] = val;
}

// ---- prep: blend W fragment pack: [wtile 0..15][kc][lane][e], n = w direct --
__global__ __launch_bounds__(512) void prep_bfrag(const float* __restrict__ Wm,
                                                  f16* __restrict__ dst) {
  int blk = blockIdx.x;            // wtile*48 + kc   (grid 16*48 = 768)
  int wtile = blk / KC, kc = blk % KC;
  int t = threadIdx.x;
  int l = t >> 3, e = t & 7;
  int c = l & 15, kg = l >> 4;
  int n = wtile * 16 + c;          // w in [0,256)
  int keff = kc * 32 + kg * 8 + e;
  int kblk = keff >> 9, k = keff & 511;
  float w = Wm[(size_t)n * 512 + k];
  f16 hi = (f16)w;
  float lo = w - (float)hi;
  f16 val = (kblk < 2) ? hi : (f16)(lo * 2048.0f);
  dst[(size_t)blk * 512 + t] = val;
}

// ---------------- prep: encInP[v][j*4+g] = emb[v].Wih[g*512+j] + bih + bhh ---
__global__ __launch_bounds__(256) void prep_encin(
    const float* __restrict__ emb, const float* __restrict__ Wih,
    const float* __restrict__ bih, const float* __restrict__ bhh,
    float* __restrict__ encInP) {
  int wid = blockIdx.x * 4 + (threadIdx.x >> 6);
  int lane = threadIdx.x & 63;
  if (wid >= Vsz * 2048) return;
  int v = wid >> 11, col = wid & 2047;
  float4 e = ((const float4*)emb)[v * 64 + lane];
  float4 w = ((const float4*)Wih)[col * 64 + lane];
  float d = e.x * w.x + e.y * w.y + e.z * w.z + e.w * w.w;
  for (int off = 32; off; off >>= 1) d += __shfl_xor(d, off);
  if (lane == 0) {
    int g = col >> 9, j = col & 511;
    encInP[(size_t)v * 2048 + j * 4 + g] = d + bih[col] + bhh[col];
  }
}

// ---------------- prep: dbiasP[j*4+g] = dec_bih + dec_bhh ----------------
__global__ __launch_bounds__(256) void prep_dbias(const float* __restrict__ a,
                                                  const float* __restrict__ b,
                                                  float* __restrict__ dst) {
  int col = blockIdx.x * 256 + threadIdx.x;  // < 2048
  int g = col >> 9, j = col & 511;
  dst[j * 4 + g] = a[col] + b[col];
}

// ---------------- fused gates MFMA GEMM + LSTM cell ----------------
// fp16x3 MFMA, fragment-major A/B (1KB coalesced frag loads, no LDS/barrier
// in K-loop).  r5 occupancy fix: tile 64b x 128n', grid 512 = 2 blocks/CU =
// 2 waves/SIMD (was 1) so co-resident waves hide each other's L2 latency.
// Block: 256 thr = 4 waves (2m x 2n); wave = 32b x 64n' (A x2, B x4,
// 8 MFMA/kc).  XCD swizzle kept: XCD x owns b-rows [256x,256x+256),
// self-consistent with the h-frag producer/consumer across dispatches.
__global__ __launch_bounds__(256, 2) void gates_mfma(
    const f16* __restrict__ Afrag,   // h16' [128 mt][48 kc][64 lane][8]
    const f16* __restrict__ Bfrag,   // W'   [128 nt][48 kc][64 lane][8]
    const float* __restrict__ addtab, const int* __restrict__ input, int tstep,
    f16* __restrict__ Aout,          // next h16', fragment-major
    float* __restrict__ cio) {       // [2048][512] f32
  __shared__ float Cst[64][132];
  const int t = threadIdx.x;
  const int lane = t & 63;
  const int wid = t >> 6;
  const int wm = wid >> 1, wn = wid & 1;
  const int bid = blockIdx.x;
  const int xcd = bid & 7, loc = bid >> 3;          // loc in [0,64)
  const int mblk = xcd * 4 + (loc >> 4);            // 0..31 (64-b tiles)
  const int nblk = loc & 15;                        // 0..15 (128-n' tiles)

  const f16* Ab = Afrag + (((size_t)(mblk * 4 + wm * 2) * KC) * 64 + lane) * 8;
  const f16* Bb = Bfrag + (((size_t)(nblk * 8 + wn * 4) * KC) * 64 + lane) * 8;

  f32x4 acc[2][4];
  {
    f32x4 z = {0.f, 0.f, 0.f, 0.f};
#pragma unroll
    for (int i = 0; i < 2; ++i)
#pragma unroll
      for (int j = 0; j < 4; ++j) acc[i][j] = z;
  }

  f16x8 pa[2], pb[4], qa[2], qb[4];

#define GLOAD(A_, B_, kc_)                                              \
  {                                                                     \
    _Pragma("unroll")                                                   \
    for (int q = 0; q < 2; ++q)                                         \
      A_[q] = *(const f16x8*)(Ab + ((size_t)q * KC + (kc_)) * 512);     \
    _Pragma("unroll")                                                   \
    for (int q = 0; q < 4; ++q)                                         \
      B_[q] = *(const f16x8*)(Bb + ((size_t)q * KC + (kc_)) * 512);     \
  }
#define GMM(A_, B_)                                                     \
  {                                                                     \
    _Pragma("unroll")                                                   \
    for (int mt = 0; mt < 2; ++mt)                                      \
      _Pragma("unroll")                                                 \
      for (int nt = 0; nt < 4; ++nt)                                    \
        acc[mt][nt] = __builtin_amdgcn_mfma_f32_16x16x32_f16(           \
            A_[mt], B_[nt], acc[mt][nt], 0, 0, 0);                      \
  }

  GLOAD(pa, pb, 0)
#pragma unroll 1
  for (int kc = 0; kc < KC; kc += 2) {
    GLOAD(qa, qb, kc + 1)
    GMM(pa, pb)
    if (kc + 2 < KC) GLOAD(pa, pb, kc + 2)
    GMM(qa, qb)
  }
#undef GLOAD
#undef GMM

  // ---- epilogue: single pass (Cst 64 x 132 f32 = 34KB; 2 blocks/CU ok) ----
#pragma unroll
  for (int mt = 0; mt < 2; ++mt)
#pragma unroll
    for (int nt = 0; nt < 4; ++nt)
#pragma unroll
      for (int rg = 0; rg < 4; ++rg)
        Cst[wm * 32 + mt * 16 + (lane >> 4) * 4 + rg]
           [wn * 64 + nt * 16 + (lane & 15)] = acc[mt][nt][rg];
  __syncthreads();

  const int bloc = t & 63, jg = t >> 6;
  const int bg = mblk * 64 + bloc;
  const float* arow = input
      ? addtab + (size_t)input[(size_t)bg * Ssz + tstep] * 2048
      : addtab;

  const int j0 = nblk * 32 + jg * 8;   // 8 j's per thread
  float* cp = cio + (size_t)bg * 512 + j0;
  float4 cv0 = *(const float4*)(cp);
  float4 cv1 = *(const float4*)(cp + 4);
  float cin[8] = {cv0.x, cv0.y, cv0.z, cv0.w, cv1.x, cv1.y, cv1.z, cv1.w};
  float cn[8], hv[8];
#pragma unroll
  for (int jj = 0; jj < 8; ++jj) {
    float4 gq = *(const float4*)(&Cst[bloc][jg * 32 + jj * 4]);
    float4 av = *(const float4*)(arow + (size_t)(j0 + jj) * 4);
    float gi = gq.x + av.x;
    float gf = gq.y + av.y;
    float gg = gq.z + av.z;
    float go = gq.w + av.w;
    float si = 1.0f / (1.0f + expf(-gi));
    float sf = 1.0f / (1.0f + expf(-gf));
    float sg = tanhf(gg);
    float so = 1.0f / (1.0f + expf(-go));
    float c2 = sf * cin[jj] + si * sg;
    cn[jj] = c2;
    hv[jj] = so * tanhf(c2);
  }
  *(float4*)(cp)     = make_float4(cn[0], cn[1], cn[2], cn[3]);
  *(float4*)(cp + 4) = make_float4(cn[4], cn[5], cn[6], cn[7]);

  f16x8 hi8, lo8, h28;
#pragma unroll
  for (int jj = 0; jj < 8; ++jj) {
    f16 hi = (f16)hv[jj];
    hi8[jj] = hi;
    lo8[jj] = (f16)(hv[jj] - (float)hi);
    h28[jj] = (f16)((float)hi * (1.0f / 2048.0f));
  }
  const int kcH = j0 >> 5;
  const int kg = (j0 >> 3) & 3;
  size_t base = (((size_t)(bg >> 4) * KC + kcH) * 64 + kg * 16 + (bg & 15)) * 8;
  *(f16x8*)(Aout + base)                     = hi8;   // k-block 0: hi
  *(f16x8*)(Aout + base + (size_t)16 * 512)  = lo8;   // k-block 1: lo
  *(f16x8*)(Aout + base + (size_t)32 * 512)  = h28;   // k-block 2: hi/2048
}

// ---------------- blend MFMA GEMM: out[b][w] = sum_k h[b][k]*Wm[w][k] --------
// r5 occupancy fix: 256 thr = 4 waves (2m x 2n), tile 64b x 32w, grid 256 ->
// 4 waves/CU (was 2).  Wave = 32b x 16w (A x2, B x1, 2 MFMA/kc).
// XCD swizzle aligned with gates (XCD x covers b-rows [256x,256x+256)).
__global__ __launch_bounds__(256) void blend_mfma(
    const f16* __restrict__ Afrag, const f16* __restrict__ Bfrag,
    float* __restrict__ out, int rowStride) {
  const int t = threadIdx.x, lane = t & 63, wid = t >> 6;
  const int wm = wid >> 1, wn = wid & 1;
  const int bid = blockIdx.x;
  const int xcd = bid & 7, loc = bid >> 3;          // loc in [0,32)
  const int mblk = xcd * 4 + (loc >> 3);            // 0..31 (64-b tiles)
  const int nblk = loc & 7;                         // 0..7  (32-w tiles)
  const f16* Ab = Afrag + (((size_t)(mblk * 4 + wm * 2) * KC) * 64 + lane) * 8;
  const f16* Bb = Bfrag + (((size_t)(nblk * 2 + wn) * KC) * 64 + lane) * 8;

  f32x4 acc[2];
  {
    f32x4 z = {0.f, 0.f, 0.f, 0.f};
    acc[0] = z; acc[1] = z;
  }
  f16x8 pa[2], pb, qa[2], qb;

#define BLOAD(A_, B_, kc_)                                              \
  {                                                                     \
    _Pragma("unroll")                                                   \
    for (int q = 0; q < 2; ++q)                                         \
      A_[q] = *(const f16x8*)(Ab + ((size_t)q * KC + (kc_)) * 512);     \
    B_ = *(const f16x8*)(Bb + (size_t)(kc_) * 512);                     \
  }
#define BMM(A_, B_)                                                     \
  {                                                                     \
    _Pragma("unroll")                                                   \
    for (int mt = 0; mt < 2; ++mt)                                      \
      acc[mt] = __builtin_amdgcn_mfma_f32_16x16x32_f16(                 \
          A_[mt], B_, acc[mt], 0, 0, 0);                                \
  }

  BLOAD(pa, pb, 0)
#pragma unroll 1
  for (int kc = 0; kc < KC; kc += 2) {
    BLOAD(qa, qb, kc + 1)
    BMM(pa, pb)
    if (kc + 2 < KC) BLOAD(pa, pb, kc + 2)
    BMM(qa, qb)
  }
#undef BLOAD
#undef BMM

  const int r = lane & 15, rg4 = (lane >> 4) * 4;
#pragma unroll
  for (int mt = 0; mt < 2; ++mt)
#pragma unroll
    for (int rg = 0; rg < 4; ++rg) {
      int b = mblk * 64 + wm * 32 + mt * 16 + rg4 + rg;
      int w = nblk * 32 + wn * 16 + r;
      out[(size_t)b * rowStride + w] = acc[mt][rg];
    }
}

// ---------------- decoder c0 = last encoder h (reconstruct hi+lo) ------------
__global__ __launch_bounds__(256) void dec_cinit(const f16* __restrict__ hE,
                                                 float* __restrict__ cD) {
  int idx = blockIdx.x * 256 + threadIdx.x;  // < 2048*512
  int b = idx >> 9, j = idx & 511;
  size_t base = (((size_t)(b >> 4) * KC + (j >> 5)) * 64
                 + ((j >> 3) & 3) * 16 + (b & 15)) * 8 + (j & 7);
  cD[idx] = (float)hE[base] + (float)hE[base + (size_t)16 * 512];
}

// ---------------- scores + log_softmax + gumbel sample + mask ----------------
__global__ __launch_bounds__(256) void scores_sample(
    const float* __restrict__ b1, const float* __restrict__ b2,
    const float* __restrict__ vt, unsigned long long* __restrict__ mask,
    float* __restrict__ probs, float* __restrict__ tour,
    int stepk, unsigned kA, unsigned kB) {
  __shared__ float b2s[256];
  __shared__ float vts[256];
  __shared__ float sc[52];
  const int t = threadIdx.x, b = blockIdx.x;
  b2s[t] = b2[(size_t)b * Wsz + t];
  vts[t] = vt[t];
  __syncthreads();
  const int wave = t >> 6, lane = t & 63;
  for (int s = wave; s < Ssz; s += 4) {
    const float* row = b1 + ((size_t)b * Ssz + s) * Wsz;
    float v = 0.f;
#pragma unroll
    for (int q = 0; q < 4; ++q) {
      int w = lane + 64 * q;
      v += vts[w] * tanhf(row[w] + b2s[w]);
    }
    for (int off = 32; off; off >>= 1) v += __shfl_xor(v, off);
    if (lane == 0) sc[s] = v;
  }
  __syncthreads();
  if (wave == 0) {
    unsigned long long m = mask[b];
    float x = (lane < Ssz) ? sc[lane] : -INFINITY;
    if (lane < Ssz && ((m >> lane) & 1ull)) x = -100000.0f;
    float mv = x;
    for (int off = 32; off; off >>= 1) mv = fmaxf(mv, __shfl_xor(mv, off));
    float sh = x - mv;
    float e = (lane < Ssz) ? expf(sh) : 0.f;
    float ssum = e;
    for (int off = 32; off; off >>= 1) ssum += __shfl_xor(ssum, off);
    float lg = logf(ssum);
    float logp = sh - lg;
    if (lane < Ssz) probs[(size_t)b * (Lsz * Ssz) + stepk * Ssz + lane] = logp;

    float val = -INFINITY;
    if (lane < Ssz) {
      unsigned j = (unsigned)(b * Ssz + lane);
      unsigned o0, o1, bits;
#if JAX_THREEFRY_PARTITIONABLE
      threefry2x32_hd(kA, kB, 0u, j, o0, o1);
      bits = o0 ^ o1;
#else
      if (j < 51200u) { threefry2x32_hd(kA, kB, j, j + 51200u, o0, o1); bits = o0; }
      else           { threefry2x32_hd(kA, kB, j - 51200u, j, o0, o1); bits = o1; }
#endif
      float f = __uint_as_float((bits >> 9) | 0x3F800000u) - 1.0f;
      float u = fmaxf(1.17549435e-38f, f + 1.17549435e-38f);
      val = logp - logf(-logf(u));
    }
    int idx = lane;
    for (int off = 32; off; off >>= 1) {
      float ov = __shfl_xor(val, off);
      int oi = __shfl_xor(idx, off);
      if (ov > val || (ov == val && oi < idx)) { val = ov; idx = oi; }
    }
    if (lane == 0) {
      tour[(size_t)b * Lsz + stepk] = (float)idx;
      mask[b] = m | (1ull << idx);
    }
  }
}

extern "C" void kernel_launch(void* const* d_in, const int* in_sizes, int n_in,
                              void* d_out, int out_size, void* d_ws, size_t ws_size,
                              hipStream_t stream) {
  (void)in_sizes; (void)n_in; (void)out_size; (void)ws_size;
  const int*   input = (const int*)d_in[0];
  const float* emb   = (const float*)d_in[1];
  const float* eWih  = (const float*)d_in[2];
  const float* eWhh  = (const float*)d_in[3];
  const float* ebih  = (const float*)d_in[4];
  const float* ebhh  = (const float*)d_in[5];
  /* d_in[6] dec_Wih unused: decoder input is always zero */
  const float* dWhh  = (const float*)d_in[7];
  const float* dbih  = (const float*)d_in[8];
  const float* dbhh  = (const float*)d_in[9];
  const float* W1    = (const float*)d_in[10];
  const float* W2    = (const float*)d_in[11];
  const float* vt    = (const float*)d_in[12];
  float* outF = (float*)d_out;

  float* wsf = (float*)d_ws;
  size_t o = 0;
  const size_t GFRAG = (size_t)128 * KC * 512;  // f16 count = 3,145,728 (6MB)
  const size_t BFRAG = (size_t)16 * KC * 512;   // f16 count = 393,216
  f16* BfE = (f16*)(wsf + o); o += GFRAG / 2;   // enc gates W frag pack
  f16* BfD = (f16*)(wsf + o); o += GFRAG / 2;   // dec gates W frag pack
  f16* Bb1 = (f16*)(wsf + o); o += BFRAG / 2;   // W1 blend frag pack
  f16* Bb2 = (f16*)(wsf + o); o += BFRAG / 2;   // W2 blend frag pack
  float* encInP = wsf + o; o += (size_t)Vsz * 2048;
  float* dbiasP = wsf + o; o += 2048;
  f16* hEA = (f16*)(wsf + o); o += GFRAG / 2;   // encoder h16' dbuf
  f16* hEB = (f16*)(wsf + o); o += GFRAG / 2;
  f16* hDA = (f16*)(wsf + o); o += GFRAG / 2;   // decoder h16' dbuf
  f16* hDB = (f16*)(wsf + o); o += GFRAG / 2;
  float* cE  = wsf + o; o += (size_t)Bsz * Hsz;  // enc c, reused as dec c
  float* b2  = wsf + o; o += (size_t)Bsz * Wsz;
  float* b1  = wsf + o; o += (size_t)Bsz * Ssz * Wsz;
  unsigned long long* maskp = (unsigned long long*)(wsf + o); o += Bsz * 2;

  hipMemsetAsync(hEA, 0, GFRAG * 2, stream);
  hipMemsetAsync(hDA, 0, GFRAG * 2, stream);
  hipMemsetAsync(cE, 0, (size_t)Bsz * Hsz * 4, stream);
  hipMemsetAsync(maskp, 0, (size_t)Bsz * 8, stream);

  prep_gfrag<<<128 * KC, 512, 0, stream>>>(eWhh, BfE);
  prep_gfrag<<<128 * KC, 512, 0, stream>>>(dWhh, BfD);
  prep_bfrag<<<16 * KC, 512, 0, stream>>>(W1, Bb1);
  prep_bfrag<<<16 * KC, 512, 0, stream>>>(W2, Bb2);
  prep_encin<<<(Vsz * 2048) / 4, 256, 0, stream>>>(emb, eWih, ebih, ebhh, encInP);
  prep_dbias<<<8, 256, 0, stream>>>(dbih, dbhh, dbiasP);

  // host-side: step keys = jax.random.split(jax.random.key(42), 50)
  unsigned kAh[Lsz], kBh[Lsz];
  for (int k = 0; k < Lsz; ++k) {
#if JAX_THREEFRY_PARTITIONABLE
    threefry2x32_hd(0u, 42u, 0u, (unsigned)k, kAh[k], kBh[k]);
#else
    unsigned a0, a1, c0, c1;
    if (k < 25) {
      threefry2x32_hd(0u, 42u, 2u * k,      2u * k + 50u, a0, a1); kAh[k] = a0;
      threefry2x32_hd(0u, 42u, 2u * k + 1u, 2u * k + 51u, c0, c1); kBh[k] = c0;
    } else {
      threefry2x32_hd(0u, 42u, 2u * k - 50u, 2u * k,      a0, a1); kAh[k] = a1;
      threefry2x32_hd(0u, 42u, 2u * k - 49u, 2u * k + 1u, c0, c1); kBh[k] = c1;
    }
#endif
  }

  // encoder
  f16* hr = hEA; f16* hw = hEB;
  for (int t = 0; t < Ssz; ++t) {
    gates_mfma<<<512, 256, 0, stream>>>(hr, BfE, encInP, input, t, hw, cE);
    blend_mfma<<<256, 256, 0, stream>>>(hw, Bb1, b1 + (size_t)t * Wsz, Ssz * Wsz);
    f16* tp = hr; hr = hw; hw = tp;
  }
  // decoder init: c0 = last encoder h (hi+lo reconstruct), h0 = 0, mask = 0
  dec_cinit<<<(Bsz * Hsz) / 256, 256, 0, stream>>>(hr, cE);

  f16* dr = hDA; f16* dw = hDB;
  for (int k = 0; k < Lsz; ++k) {
    gates_mfma<<<512, 256, 0, stream>>>(dr, BfD, dbiasP, nullptr, 0, dw, cE);
    blend_mfma<<<256, 256, 0, stream>>>(dw, Bb2, b2, Wsz);
    scores_sample<<<Bsz, 256, 0, stream>>>(b1, b2, vt, maskp, outF,
                                           outF + (size_t)Bsz * Lsz * Ssz,
                                           k, kAh[k], kBh[k]);
    f16* tp = dr; dr = dw; dw = tp;
  }
}

// Round 7
// 4822.261 us; speedup vs baseline: 3.3003x; 1.0851x over previous
//
#include <hip/hip_runtime.h>
#include <cstdint>

// Problem constants
#define Bsz 2048
#define Ssz 50
#define Esz 256
#define Hsz 512
#define Wsz 256
#define Lsz 50
#define Vsz 51
#define KC 48   // k-chunks of 32 over K_eff = 1536 (fp16x3 split)
#define CH 5    // steps per blend chunk
#define GFRAGC ((size_t)128 * KC * 512)   // f16 elems per h/W gates frag buffer

// JAX RNG semantics: 1 = threefry_partitionable (jax >= 0.4.36 default), 0 = original
#define JAX_THREEFRY_PARTITIONABLE 1

typedef _Float16 f16;
typedef _Float16 f16x8 __attribute__((ext_vector_type(8)));
typedef float f32x4 __attribute__((ext_vector_type(4)));

// ---------------- threefry2x32 (20 rounds), key words (k0,k1) ----------------
__host__ __device__ __forceinline__ void threefry2x32_hd(
    unsigned k0, unsigned k1, unsigned x0, unsigned x1,
    unsigned& o0, unsigned& o1) {
  unsigned ks2 = k0 ^ k1 ^ 0x1BD11BDAu;
  x0 += k0; x1 += k1;
#define TF_RND(r) { x0 += x1; x1 = (x1 << (r)) | (x1 >> (32 - (r))); x1 ^= x0; }
  TF_RND(13) TF_RND(15) TF_RND(26) TF_RND(6)
  x0 += k1; x1 += ks2 + 1u;
  TF_RND(17) TF_RND(29) TF_RND(16) TF_RND(24)
  x0 += ks2; x1 += k0 + 2u;
  TF_RND(13) TF_RND(15) TF_RND(26) TF_RND(6)
  x0 += k0; x1 += k1 + 3u;
  TF_RND(17) TF_RND(29) TF_RND(16) TF_RND(24)
  x0 += k1; x1 += ks2 + 4u;
  TF_RND(13) TF_RND(15) TF_RND(26) TF_RND(6)
  x0 += ks2; x1 += k0 + 5u;
#undef TF_RND
  o0 = x0; o1 = x1;
}

// ---- prep: gates W fragment pack, kc-OUTER layout ----
// dst[(kc*128 + ntile)*512 + l*8 + e] = Wf16[n = ntile*16 + c][keff],
// l = kg*16 + c, keff = kc*32 + kg*8 + e.  n' = j*4+g (gate-interleaved).
// Wf16 k-blocks = [Whi | Whi | Wlo*2048] (fp16x3).
// kc-outer makes a wave's q-frags base+q*1KB (13-bit imm offsets) and the
// kc-advance a single pointer add -> kills the per-kc 64-bit address VALU.
__global__ __launch_bounds__(512) void prep_gfrag(const float* __restrict__ Whh,
                                                  f16* __restrict__ dst) {
  int blk = blockIdx.x;            // ntile*48 + kc   (grid 128*48 = 6144)
  int ntile = blk / KC, kc = blk % KC;
  int t = threadIdx.x;             // 512 = l*8 + e
  int l = t >> 3, e = t & 7;
  int c = l & 15, kg = l >> 4;
  int n = ntile * 16 + c;          // n' in [0,2048)
  int keff = kc * 32 + kg * 8 + e;
  int kblk = keff >> 9, k = keff & 511;
  int j = n >> 2, g = n & 3;
  float w = Whh[(size_t)(g * 512 + j) * 512 + k];
  f16 hi = (f16)w;
  float lo = w - (float)hi;
  f16 val = (kblk < 2) ? hi : (f16)(lo * 2048.0f);
  dst[((size_t)kc * 128 + ntile) * 512 + t] = val;
}

// ---- prep: blend W pack, kc-outer: dst[(kc*16 + wtile)*512 + t] ----
__global__ __launch_bounds__(512) void prep_bfrag(const float* __restrict__ Wm,
                                                  f16* __restrict__ dst) {
  int blk = blockIdx.x;            // wtile*48 + kc   (grid 16*48 = 768)
  int wtile = blk / KC, kc = blk % KC;
  int t = threadIdx.x;
  int l = t >> 3, e = t & 7;
  int c = l & 15, kg = l >> 4;
  int n = wtile * 16 + c;          // w in [0,256)
  int keff = kc * 32 + kg * 8 + e;
  int kblk = keff >> 9, k = keff & 511;
  float w = Wm[(size_t)n * 512 + k];
  f16 hi = (f16)w;
  float lo = w - (float)hi;
  f16 val = (kblk < 2) ? hi : (f16)(lo * 2048.0f);
  dst[((size_t)kc * 16 + wtile) * 512 + t] = val;
}

// ---------------- prep: encInP[v][j*4+g] = emb[v].Wih[g*512+j] + bih + bhh ---
__global__ __launch_bounds__(256) void prep_encin(
    const float* __restrict__ emb, const float* __restrict__ Wih,
    const float* __restrict__ bih, const float* __restrict__ bhh,
    float* __restrict__ encInP) {
  int wid = blockIdx.x * 4 + (threadIdx.x >> 6);
  int lane = threadIdx.x & 63;
  if (wid >= Vsz * 2048) return;
  int v = wid >> 11, col = wid & 2047;
  float4 e = ((const float4*)emb)[v * 64 + lane];
  float4 w = ((const float4*)Wih)[col * 64 + lane];
  float d = e.x * w.x + e.y * w.y + e.z * w.z + e.w * w.w;
  for (int off = 32; off; off >>= 1) d += __shfl_xor(d, off);
  if (lane == 0) {
    int g = col >> 9, j = col & 511;
    encInP[(size_t)v * 2048 + j * 4 + g] = d + bih[col] + bhh[col];
  }
}

// ---------------- prep: dbiasP[j*4+g] = dec_bih + dec_bhh ----------------
__global__ __launch_bounds__(256) void prep_dbias(const float* __restrict__ a,
                                                  const float* __restrict__ b,
                                                  float* __restrict__ dst) {
  int col = blockIdx.x * 256 + threadIdx.x;  // < 2048
  int g = col >> 9, j = col & 511;
  dst[j * 4 + g] = a[col] + b[col];
}

// ---------------- fused gates MFMA GEMM + LSTM cell ----------------
// fp16x3 MFMA, fragment-major kc-outer A/B.  Tile 64b x 128n', grid 512 =
// 2 blocks/CU (2 waves/SIMD).  Block: 4 waves (2m x 2n); wave = 32b x 64n'
// (A x2, B x4, 8 MFMA/kc).  Frag loads: base + q*1KB imm offsets, one
// pointer add per kc.  XCD swizzle kept (h rows self-consistent per XCD).
__global__ __launch_bounds__(256, 2) void gates_mfma(
    const f16* __restrict__ Afrag,   // h16' [48 kc][128 mt][64 lane][8]
    const f16* __restrict__ Bfrag,   // W'   [48 kc][128 nt][64 lane][8]
    const float* __restrict__ addtab, const int* __restrict__ input, int tstep,
    f16* __restrict__ Aout,          // next h16', same layout
    float* __restrict__ cio) {       // [2048][512] f32
  __shared__ float Cst[64][132];
  const int t = threadIdx.x;
  const int lane = t & 63;
  const int wid = t >> 6;
  const int wm = wid >> 1, wn = wid & 1;
  const int bid = blockIdx.x;
  const int xcd = bid & 7, loc = bid >> 3;          // loc in [0,64)
  const int mblk = xcd * 4 + (loc >> 4);            // 0..31 (64-b tiles)
  const int nblk = loc & 15;                        // 0..15 (128-n' tiles)

  const f16* Ab = Afrag + (size_t)(mblk * 4 + wm * 2) * 512 + lane * 8;
  const f16* Bb = Bfrag + (size_t)(nblk * 8 + wn * 4) * 512 + lane * 8;

  f32x4 acc[2][4];
  {
    f32x4 z = {0.f, 0.f, 0.f, 0.f};
#pragma unroll
    for (int i = 0; i < 2; ++i)
#pragma unroll
      for (int j = 0; j < 4; ++j) acc[i][j] = z;
  }

  f16x8 pa[2], pb[4], qa[2], qb[4];

#define GLOAD(A_, B_, kc_)                                                   \
  {                                                                          \
    const f16* ak = Ab + (size_t)(kc_)*65536;                                \
    const f16* bk = Bb + (size_t)(kc_)*65536;                                \
    _Pragma("unroll")                                                        \
    for (int q = 0; q < 2; ++q) A_[q] = *(const f16x8*)(ak + q * 512);       \
    _Pragma("unroll")                                                        \
    for (int q = 0; q < 4; ++q) B_[q] = *(const f16x8*)(bk + q * 512);       \
  }
#define GMM(A_, B_)                                                          \
  {                                                                          \
    _Pragma("unroll")                                                        \
    for (int mt = 0; mt < 2; ++mt)                                           \
      _Pragma("unroll")                                                      \
      for (int nt = 0; nt < 4; ++nt)                                         \
        acc[mt][nt] = __builtin_amdgcn_mfma_f32_16x16x32_f16(                \
            A_[mt], B_[nt], acc[mt][nt], 0, 0, 0);                           \
  }

  GLOAD(pa, pb, 0)
#pragma unroll 1
  for (int kc = 0; kc < KC; kc += 2) {
    GLOAD(qa, qb, kc + 1)
    GMM(pa, pb)
    if (kc + 2 < KC) GLOAD(pa, pb, kc + 2)
    GMM(qa, qb)
  }
#undef GLOAD
#undef GMM

  // ---- epilogue: Cst 64 x 132 f32 = 34KB; 2 blocks/CU ok ----
#pragma unroll
  for (int mt = 0; mt < 2; ++mt)
#pragma unroll
    for (int nt = 0; nt < 4; ++nt)
#pragma unroll
      for (int rg = 0; rg < 4; ++rg)
        Cst[wm * 32 + mt * 16 + (lane >> 4) * 4 + rg]
           [wn * 64 + nt * 16 + (lane & 15)] = acc[mt][nt][rg];
  __syncthreads();

  const int bloc = t & 63, jg = t >> 6;
  const int bg = mblk * 64 + bloc;
  const float* arow = input
      ? addtab + (size_t)input[(size_t)bg * Ssz + tstep] * 2048
      : addtab;

  const int j0 = nblk * 32 + jg * 8;   // 8 j's per thread
  float* cp = cio + (size_t)bg * 512 + j0;
  float4 cv0 = *(const float4*)(cp);
  float4 cv1 = *(const float4*)(cp + 4);
  float cin[8] = {cv0.x, cv0.y, cv0.z, cv0.w, cv1.x, cv1.y, cv1.z, cv1.w};
  float cn[8], hv[8];
#pragma unroll
  for (int jj = 0; jj < 8; ++jj) {
    float4 gq = *(const float4*)(&Cst[bloc][jg * 32 + jj * 4]);
    float4 av = *(const float4*)(arow + (size_t)(j0 + jj) * 4);
    float gi = gq.x + av.x;
    float gf = gq.y + av.y;
    float gg = gq.z + av.z;
    float go = gq.w + av.w;
    float si = 1.0f / (1.0f + expf(-gi));
    float sf = 1.0f / (1.0f + expf(-gf));
    float sg = tanhf(gg);
    float so = 1.0f / (1.0f + expf(-go));
    float c2 = sf * cin[jj] + si * sg;
    cn[jj] = c2;
    hv[jj] = so * tanhf(c2);
  }
  *(float4*)(cp)     = make_float4(cn[0], cn[1], cn[2], cn[3]);
  *(float4*)(cp + 4) = make_float4(cn[4], cn[5], cn[6], cn[7]);

  f16x8 hi8, lo8, h28;
#pragma unroll
  for (int jj = 0; jj < 8; ++jj) {
    f16 hi = (f16)hv[jj];
    hi8[jj] = hi;
    lo8[jj] = (f16)(hv[jj] - (float)hi);
    h28[jj] = (f16)((float)hi * (1.0f / 2048.0f));
  }
  const int kcH = j0 >> 5;             // 0..15
  const int kg = (j0 >> 3) & 3;
  size_t base = (((size_t)kcH * 128 + (bg >> 4)) * 64 + kg * 16 + (bg & 15)) * 8;
  *(f16x8*)(Aout + base)                       = hi8;  // kc-block 0: hi
  *(f16x8*)(Aout + base + (size_t)16 * 65536)  = lo8;  // kc-block 1: lo
  *(f16x8*)(Aout + base + (size_t)32 * 65536)  = h28;  // kc-block 2: hi/2048
}

// ---------------- batched blend MFMA: CH steps in one dispatch ---------------
// out[s][b][w] = sum_k h_s[b][k]*Wm[w][k].  A = CH contiguous frag buffers
// (kc-outer).  Grid = CH*32 mblkG x 8 nblk; block 256 thr = 4 waves (2m x 2n);
// wave = 32b x 16w (A x2, B x1, 2 MFMA/kc).
__global__ __launch_bounds__(256) void blend_big(
    const f16* __restrict__ hChunk, const f16* __restrict__ Wb,
    float* __restrict__ outBase, int stepStride, int rowStride) {
  const int t = threadIdx.x, lane = t & 63, wid = t >> 6;
  const int wm = wid >> 1, wn = wid & 1;
  const int bid = blockIdx.x;
  const int nblk = bid & 7;            // 8 w-blocks of 32
  const int mblkG = bid >> 3;          // 0..CH*32-1
  const int s = mblkG >> 5;            // step within chunk
  const int mblkL = mblkG & 31;
  const f16* Ab = hChunk + (size_t)s * GFRAGC
                + (size_t)(mblkL * 4 + wm * 2) * 512 + lane * 8;
  const f16* Bb = Wb + (size_t)(nblk * 2 + wn) * 512 + lane * 8;

  f32x4 acc[2];
  {
    f32x4 z = {0.f, 0.f, 0.f, 0.f};
    acc[0] = z; acc[1] = z;
  }
  f16x8 pa[2], pb, qa[2], qb;

#define BLOAD(A_, B_, kc_)                                                   \
  {                                                                          \
    const f16* ak = Ab + (size_t)(kc_)*65536;                                \
    _Pragma("unroll")                                                        \
    for (int q = 0; q < 2; ++q) A_[q] = *(const f16x8*)(ak + q * 512);       \
    B_ = *(const f16x8*)(Bb + (size_t)(kc_)*8192);                           \
  }
#define BMM(A_, B_)                                                          \
  {                                                                          \
    _Pragma("unroll")                                                        \
    for (int mt = 0; mt < 2; ++mt)                                           \
      acc[mt] = __builtin_amdgcn_mfma_f32_16x16x32_f16(                      \
          A_[mt], B_, acc[mt], 0, 0, 0);                                     \
  }

  BLOAD(pa, pb, 0)
#pragma unroll 1
  for (int kc = 0; kc < KC; kc += 2) {
    BLOAD(qa, qb, kc + 1)
    BMM(pa, pb)
    if (kc + 2 < KC) BLOAD(pa, pb, kc + 2)
    BMM(qa, qb)
  }
#undef BLOAD
#undef BMM

  const int r = lane & 15, rg4 = (lane >> 4) * 4;
  float* ob = outBase + (size_t)s * stepStride;
#pragma unroll
  for (int mt = 0; mt < 2; ++mt)
#pragma unroll
    for (int rg = 0; rg < 4; ++rg) {
      int b = mblkL * 64 + wm * 32 + mt * 16 + rg4 + rg;
      int w = nblk * 32 + wn * 16 + r;
      ob[(size_t)b * rowStride + w] = acc[mt][rg];
    }
}

// ---------------- decoder c0 = last encoder h (reconstruct hi+lo) ------------
__global__ __launch_bounds__(256) void dec_cinit(const f16* __restrict__ hE,
                                                 float* __restrict__ cD) {
  int idx = blockIdx.x * 256 + threadIdx.x;  // < 2048*512
  int b = idx >> 9, j = idx & 511;
  size_t base = (((size_t)(j >> 5) * 128 + (b >> 4)) * 64
                 + ((j >> 3) & 3) * 16 + (b & 15)) * 8 + (j & 7);
  cD[idx] = (float)hE[base] + (float)hE[base + (size_t)16 * 65536];
}

// ---------------- scores + log_softmax + gumbel sample + mask ----------------
__global__ __launch_bounds__(256) void scores_sample(
    const float* __restrict__ b1, const float* __restrict__ b2,
    const float* __restrict__ vt, unsigned long long* __restrict__ mask,
    float* __restrict__ probs, float* __restrict__ tour,
    int stepk, unsigned kA, unsigned kB) {
  __shared__ float b2s[256];
  __shared__ float vts[256];
  __shared__ float sc[52];
  const int t = threadIdx.x, b = blockIdx.x;
  b2s[t] = b2[(size_t)b * Wsz + t];
  vts[t] = vt[t];
  __syncthreads();
  const int wave = t >> 6, lane = t & 63;
  for (int s = wave; s < Ssz; s += 4) {
    const float* row = b1 + ((size_t)b * Ssz + s) * Wsz;
    float v = 0.f;
#pragma unroll
    for (int q = 0; q < 4; ++q) {
      int w = lane + 64 * q;
      v += vts[w] * tanhf(row[w] + b2s[w]);
    }
    for (int off = 32; off; off >>= 1) v += __shfl_xor(v, off);
    if (lane == 0) sc[s] = v;
  }
  __syncthreads();
  if (wave == 0) {
    unsigned long long m = mask[b];
    float x = (lane < Ssz) ? sc[lane] : -INFINITY;
    if (lane < Ssz && ((m >> lane) & 1ull)) x = -100000.0f;
    float mv = x;
    for (int off = 32; off; off >>= 1) mv = fmaxf(mv, __shfl_xor(mv, off));
    float sh = x - mv;
    float e = (lane < Ssz) ? expf(sh) : 0.f;
    float ssum = e;
    for (int off = 32; off; off >>= 1) ssum += __shfl_xor(ssum, off);
    float lg = logf(ssum);
    float logp = sh - lg;
    if (lane < Ssz) probs[(size_t)b * (Lsz * Ssz) + stepk * Ssz + lane] = logp;

    float val = -INFINITY;
    if (lane < Ssz) {
      unsigned j = (unsigned)(b * Ssz + lane);
      unsigned o0, o1, bits;
#if JAX_THREEFRY_PARTITIONABLE
      threefry2x32_hd(kA, kB, 0u, j, o0, o1);
      bits = o0 ^ o1;
#else
      if (j < 51200u) { threefry2x32_hd(kA, kB, j, j + 51200u, o0, o1); bits = o0; }
      else           { threefry2x32_hd(kA, kB, j - 51200u, j, o0, o1); bits = o1; }
#endif
      float f = __uint_as_float((bits >> 9) | 0x3F800000u) - 1.0f;
      float u = fmaxf(1.17549435e-38f, f + 1.17549435e-38f);
      val = logp - logf(-logf(u));
    }
    int idx = lane;
    for (int off = 32; off; off >>= 1) {
      float ov = __shfl_xor(val, off);
      int oi = __shfl_xor(idx, off);
      if (ov > val || (ov == val && oi < idx)) { val = ov; idx = oi; }
    }
    if (lane == 0) {
      tour[(size_t)b * Lsz + stepk] = (float)idx;
      mask[b] = m | (1ull << idx);
    }
  }
}

extern "C" void kernel_launch(void* const* d_in, const int* in_sizes, int n_in,
                              void* d_out, int out_size, void* d_ws, size_t ws_size,
                              hipStream_t stream) {
  (void)in_sizes; (void)n_in; (void)out_size; (void)ws_size;
  const int*   input = (const int*)d_in[0];
  const float* emb   = (const float*)d_in[1];
  const float* eWih  = (const float*)d_in[2];
  const float* eWhh  = (const float*)d_in[3];
  const float* ebih  = (const float*)d_in[4];
  const float* ebhh  = (const float*)d_in[5];
  /* d_in[6] dec_Wih unused: decoder input is always zero */
  const float* dWhh  = (const float*)d_in[7];
  const float* dbih  = (const float*)d_in[8];
  const float* dbhh  = (const float*)d_in[9];
  const float* W1    = (const float*)d_in[10];
  const float* W2    = (const float*)d_in[11];
  const float* vt    = (const float*)d_in[12];
  float* outF = (float*)d_out;

  float* wsf = (float*)d_ws;
  size_t o = 0;
  const size_t BFRAG = (size_t)16 * KC * 512;   // f16 count
  f16* BfE = (f16*)(wsf + o); o += GFRAGC / 2;  // enc gates W frag pack
  f16* BfD = (f16*)(wsf + o); o += GFRAGC / 2;  // dec gates W frag pack
  f16* Bb1 = (f16*)(wsf + o); o += BFRAG / 2;   // W1 blend frag pack
  f16* Bb2 = (f16*)(wsf + o); o += BFRAG / 2;   // W2 blend frag pack
  float* encInP = wsf + o; o += (size_t)Vsz * 2048;
  float* dbiasP = wsf + o; o += 2048;
  f16* hZero = (f16*)(wsf + o); o += GFRAGC / 2;          // zero h frags
  f16* hBuf  = (f16*)(wsf + o); o += CH * (GFRAGC / 2);   // CH rolling h frags
  float* cE  = wsf + o; o += (size_t)Bsz * Hsz;           // enc c, then dec c
  float* b2c = wsf + o; o += (size_t)CH * Bsz * Wsz;      // dec b2 chunk
  float* b1  = wsf + o; o += (size_t)Bsz * Ssz * Wsz;
  unsigned long long* maskp = (unsigned long long*)(wsf + o); o += Bsz * 2;

  hipMemsetAsync(hZero, 0, GFRAGC * 2, stream);
  hipMemsetAsync(cE, 0, (size_t)Bsz * Hsz * 4, stream);
  hipMemsetAsync(maskp, 0, (size_t)Bsz * 8, stream);

  prep_gfrag<<<128 * KC, 512, 0, stream>>>(eWhh, BfE);
  prep_gfrag<<<128 * KC, 512, 0, stream>>>(dWhh, BfD);
  prep_bfrag<<<16 * KC, 512, 0, stream>>>(W1, Bb1);
  prep_bfrag<<<16 * KC, 512, 0, stream>>>(W2, Bb2);
  prep_encin<<<(Vsz * 2048) / 4, 256, 0, stream>>>(emb, eWih, ebih, ebhh, encInP);
  prep_dbias<<<8, 256, 0, stream>>>(dbih, dbhh, dbiasP);

  // host-side: step keys = jax.random.split(jax.random.key(42), 50)
  unsigned kAh[Lsz], kBh[Lsz];
  for (int k = 0; k < Lsz; ++k) {
#if JAX_THREEFRY_PARTITIONABLE
    threefry2x32_hd(0u, 42u, 0u, (unsigned)k, kAh[k], kBh[k]);
#else
    unsigned a0, a1, c0, c1;
    if (k < 25) {
      threefry2x32_hd(0u, 42u, 2u * k,      2u * k + 50u, a0, a1); kAh[k] = a0;
      threefry2x32_hd(0u, 42u, 2u * k + 1u, 2u * k + 51u, c0, c1); kBh[k] = c0;
    } else {
      threefry2x32_hd(0u, 42u, 2u * k - 50u, 2u * k,      a0, a1); kAh[k] = a1;
      threefry2x32_hd(0u, 42u, 2u * k - 49u, 2u * k + 1u, c0, c1); kBh[k] = c1;
    }
#endif
  }

  const size_t GF = GFRAGC;  // f16 stride per step buffer

  // encoder: CH gates steps into rolling frag buffers, then one batched blend
  for (int c = 0; c < Ssz / CH; ++c) {
    for (int s = 0; s < CH; ++s) {
      int t = c * CH + s;
      const f16* in = (t == 0) ? hZero : hBuf + (size_t)((t - 1) % CH) * GF;
      gates_mfma<<<512, 256, 0, stream>>>(in, BfE, encInP, input, t,
                                          hBuf + (size_t)s * GF, cE);
    }
    blend_big<<<CH * 256, 256, 0, stream>>>(hBuf, Bb1,
                                            b1 + (size_t)(c * CH) * Wsz,
                                            Wsz, Ssz * Wsz);
  }
  // decoder init: c0 = last encoder h (hi+lo), h0 = 0, mask = 0
  dec_cinit<<<(Bsz * Hsz) / 256, 256, 0, stream>>>(hBuf + (size_t)((Ssz - 1) % CH) * GF, cE);

  // decoder: gates x CH -> batched blend -> scores x CH (serial mask chain)
  for (int c = 0; c < Lsz / CH; ++c) {
    for (int s = 0; s < CH; ++s) {
      int k = c * CH + s;
      const f16* in = (k == 0) ? hZero : hBuf + (size_t)((k - 1) % CH) * GF;
      gates_mfma<<<512, 256, 0, stream>>>(in, BfD, dbiasP, nullptr, 0,
                                          hBuf + (size_t)s * GF, cE);
    }
    blend_big<<<CH * 256, 256, 0, stream>>>(hBuf, Bb2, b2c,
                                            Bsz * Wsz, Wsz);
    for (int s = 0; s < CH; ++s) {
      int k = c * CH + s;
      scores_sample<<<Bsz, 256, 0, stream>>>(b1, b2c + (size_t)s * Bsz * Wsz,
                                             vt, maskp, outF,
                                             outF + (size_t)Bsz * Lsz * Ssz,
                                             k, kAh[k], kBh[k]);
    }
  }
}

// Round 8
// 3923.424 us; speedup vs baseline: 4.0564x; 1.2291x over previous
//
#include <hip/hip_runtime.h>
#include <cstdint>

// Problem constants
#define Bsz 2048
#define Ssz 50
#define Esz 256
#define Hsz 512
#define Wsz 256
#define Lsz 50
#define Vsz 51
#define KI 16    // paired k-iterations (each covers hi[kc], lo[kc+16])
#define CH 5     // steps per blend chunk
#define GFRAGC2 ((size_t)32 * 128 * 512)  // f16 elems per h/W gates pack (4MB)

// JAX RNG semantics: 1 = threefry_partitionable (jax >= 0.4.36 default), 0 = original
#define JAX_THREEFRY_PARTITIONABLE 1

typedef _Float16 f16;
typedef _Float16 f16x8 __attribute__((ext_vector_type(8)));
typedef float f32x4 __attribute__((ext_vector_type(4)));

// ---------------- threefry2x32 (20 rounds), key words (k0,k1) ----------------
__host__ __device__ __forceinline__ void threefry2x32_hd(
    unsigned k0, unsigned k1, unsigned x0, unsigned x1,
    unsigned& o0, unsigned& o1) {
  unsigned ks2 = k0 ^ k1 ^ 0x1BD11BDAu;
  x0 += k0; x1 += k1;
#define TF_RND(r) { x0 += x1; x1 = (x1 << (r)) | (x1 >> (32 - (r))); x1 ^= x0; }
  TF_RND(13) TF_RND(15) TF_RND(26) TF_RND(6)
  x0 += k1; x1 += ks2 + 1u;
  TF_RND(17) TF_RND(29) TF_RND(16) TF_RND(24)
  x0 += ks2; x1 += k0 + 2u;
  TF_RND(13) TF_RND(15) TF_RND(26) TF_RND(6)
  x0 += k0; x1 += k1 + 3u;
  TF_RND(17) TF_RND(29) TF_RND(16) TF_RND(24)
  x0 += k1; x1 += ks2 + 4u;
  TF_RND(13) TF_RND(15) TF_RND(26) TF_RND(6)
  x0 += ks2; x1 += k0 + 5u;
#undef TF_RND
  o0 = x0; o1 = x1;
}

// ---- prep: gates W pack, dual-acc fp16x3 layout ----
// dst[(kc*128 + ntile)*512 + l*8 + e]: kc in [0,16) = Whi, kc in [16,32) =
// Wlo*2048 (same k range).  k = (kc&15)*32 + kg*8 + e; n' = j*4+g.
// Third fp16x3 term uses the SAME hi A-frags with a separate accumulator
// (scaled 2^-11 at epilogue) -> packs shrink 1536->1024 k-rows (-33% bytes).
__global__ __launch_bounds__(512) void prep_gfrag(const float* __restrict__ Whh,
                                                  f16* __restrict__ dst) {
  int blk = blockIdx.x;            // ntile*32 + kc   (grid 128*32 = 4096)
  int ntile = blk >> 5, kc = blk & 31;
  int t = threadIdx.x;             // 512 = l*8 + e
  int l = t >> 3, e = t & 7;
  int c = l & 15, kg = l >> 4;
  int n = ntile * 16 + c;          // n' in [0,2048)
  int k = (kc & 15) * 32 + kg * 8 + e;
  int j = n >> 2, g = n & 3;
  float w = Whh[(size_t)(g * 512 + j) * 512 + k];
  f16 hi = (f16)w;
  float lo = w - (float)hi;
  f16 val = (kc < 16) ? hi : (f16)(lo * 2048.0f);
  dst[((size_t)kc * 128 + ntile) * 512 + t] = val;
}

// ---- prep: blend W pack: [kc 0..31][wtile 0..15][512]; kc>=16 = Wlo*2048 ----
__global__ __launch_bounds__(512) void prep_bfrag(const float* __restrict__ Wm,
                                                  f16* __restrict__ dst) {
  int blk = blockIdx.x;            // wtile*32 + kc   (grid 16*32 = 512)
  int wtile = blk >> 5, kc = blk & 31;
  int t = threadIdx.x;
  int l = t >> 3, e = t & 7;
  int c = l & 15, kg = l >> 4;
  int n = wtile * 16 + c;          // w in [0,256)
  int k = (kc & 15) * 32 + kg * 8 + e;
  float w = Wm[(size_t)n * 512 + k];
  f16 hi = (f16)w;
  float lo = w - (float)hi;
  f16 val = (kc < 16) ? hi : (f16)(lo * 2048.0f);
  dst[((size_t)kc * 16 + wtile) * 512 + t] = val;
}

// ---------------- prep: encInP[v][j*4+g] = emb[v].Wih[g*512+j] + bih + bhh ---
__global__ __launch_bounds__(256) void prep_encin(
    const float* __restrict__ emb, const float* __restrict__ Wih,
    const float* __restrict__ bih, const float* __restrict__ bhh,
    float* __restrict__ encInP) {
  int wid = blockIdx.x * 4 + (threadIdx.x >> 6);
  int lane = threadIdx.x & 63;
  if (wid >= Vsz * 2048) return;
  int v = wid >> 11, col = wid & 2047;
  float4 e = ((const float4*)emb)[v * 64 + lane];
  float4 w = ((const float4*)Wih)[col * 64 + lane];
  float d = e.x * w.x + e.y * w.y + e.z * w.z + e.w * w.w;
  for (int off = 32; off; off >>= 1) d += __shfl_xor(d, off);
  if (lane == 0) {
    int g = col >> 9, j = col & 511;
    encInP[(size_t)v * 2048 + j * 4 + g] = d + bih[col] + bhh[col];
  }
}

// ---------------- prep: dbiasP[j*4+g] = dec_bih + dec_bhh ----------------
__global__ __launch_bounds__(256) void prep_dbias(const float* __restrict__ a,
                                                  const float* __restrict__ b,
                                                  float* __restrict__ dst) {
  int col = blockIdx.x * 256 + threadIdx.x;  // < 2048
  int g = col >> 9, j = col & 511;
  dst[j * 4 + g] = a[col] + b[col];
}

// ---------------- fused gates MFMA GEMM + LSTM cell ----------------
// Dual-acc fp16x3: acc1 += hi*Whi + lo*Whi, acc2 += hi*(Wlo*2048);
// C = acc1 + acc2*2^-11.  A/B packs 1024 k-rows (4MB each).
// Tile 64b x 128n', grid 512 = 2 blocks/CU.  Block: 4 waves (2m x 2n);
// wave = 32b x 64n' (12 loads, 24 MFMA per paired iter).  XCD swizzle:
// XCD x owns b-rows [256x,256x+256) (A producer/consumer L2-local).
__global__ __launch_bounds__(256, 2) void gates_mfma(
    const f16* __restrict__ Afrag,   // h16' [32 kc][128 mt][64 lane][8]
    const f16* __restrict__ Bfrag,   // W'   [32 kc][128 nt][64 lane][8]
    const float* __restrict__ addtab, const int* __restrict__ input, int tstep,
    f16* __restrict__ Aout,          // next h16', same layout
    float* __restrict__ cio) {       // [2048][512] f32
  __shared__ float Cst[64][132];
  const int t = threadIdx.x;
  const int lane = t & 63;
  const int wid = t >> 6;
  const int wm = wid >> 1, wn = wid & 1;
  const int bid = blockIdx.x;
  const int xcd = bid & 7, loc = bid >> 3;          // loc in [0,64)
  const int mblk = xcd * 4 + (loc >> 4);            // 0..31 (64-b tiles)
  const int nblk = loc & 15;                        // 0..15 (128-n' tiles)

  const f16* Ab = Afrag + (size_t)(mblk * 4 + wm * 2) * 512 + lane * 8;
  const f16* Bb = Bfrag + (size_t)(nblk * 8 + wn * 4) * 512 + lane * 8;

  f32x4 acc1[2][4], acc2[2][4];
  {
    f32x4 z = {0.f, 0.f, 0.f, 0.f};
#pragma unroll
    for (int i = 0; i < 2; ++i)
#pragma unroll
      for (int j = 0; j < 4; ++j) { acc1[i][j] = z; acc2[i][j] = z; }
  }

  f16x8 pah[2], pal[2], pbh[4], pbl[4];
  f16x8 qah[2], qal[2], qbh[4], qbl[4];

#define GLOAD(AH_, AL_, BH_, BL_, ki_)                                        \
  {                                                                           \
    const f16* ak = Ab + (size_t)(ki_)*65536;                                 \
    const f16* bk = Bb + (size_t)(ki_)*65536;                                 \
    _Pragma("unroll")                                                         \
    for (int q = 0; q < 2; ++q) {                                             \
      AH_[q] = *(const f16x8*)(ak + q * 512);                                 \
      AL_[q] = *(const f16x8*)(ak + (size_t)16 * 65536 + q * 512);            \
    }                                                                         \
    _Pragma("unroll")                                                         \
    for (int q = 0; q < 4; ++q) {                                             \
      BH_[q] = *(const f16x8*)(bk + q * 512);                                 \
      BL_[q] = *(const f16x8*)(bk + (size_t)16 * 65536 + q * 512);            \
    }                                                                         \
  }
#define GMM(AH_, AL_, BH_, BL_)                                               \
  {                                                                           \
    _Pragma("unroll")                                                         \
    for (int mt = 0; mt < 2; ++mt)                                            \
      _Pragma("unroll")                                                       \
      for (int nt = 0; nt < 4; ++nt)                                          \
        acc1[mt][nt] = __builtin_amdgcn_mfma_f32_16x16x32_f16(                \
            AH_[mt], BH_[nt], acc1[mt][nt], 0, 0, 0);                         \
    _Pragma("unroll")                                                         \
    for (int mt = 0; mt < 2; ++mt)                                            \
      _Pragma("unroll")                                                       \
      for (int nt = 0; nt < 4; ++nt)                                          \
        acc1[mt][nt] = __builtin_amdgcn_mfma_f32_16x16x32_f16(                \
            AL_[mt], BH_[nt], acc1[mt][nt], 0, 0, 0);                         \
    _Pragma("unroll")                                                         \
    for (int mt = 0; mt < 2; ++mt)                                            \
      _Pragma("unroll")                                                       \
      for (int nt = 0; nt < 4; ++nt)                                          \
        acc2[mt][nt] = __builtin_amdgcn_mfma_f32_16x16x32_f16(                \
            AH_[mt], BL_[nt], acc2[mt][nt], 0, 0, 0);                         \
  }

  GLOAD(pah, pal, pbh, pbl, 0)
#pragma unroll 1
  for (int ki = 0; ki < KI; ki += 2) {
    GLOAD(qah, qal, qbh, qbl, ki + 1)
    GMM(pah, pal, pbh, pbl)
    if (ki + 2 < KI) GLOAD(pah, pal, pbh, pbl, ki + 2)
    GMM(qah, qal, qbh, qbl)
  }
#undef GLOAD
#undef GMM

  // ---- epilogue: combine accs, restage via LDS (Cst 34KB; 2 blocks/CU) ----
#pragma unroll
  for (int mt = 0; mt < 2; ++mt)
#pragma unroll
    for (int nt = 0; nt < 4; ++nt)
#pragma unroll
      for (int rg = 0; rg < 4; ++rg)
        Cst[wm * 32 + mt * 16 + (lane >> 4) * 4 + rg]
           [wn * 64 + nt * 16 + (lane & 15)] =
            acc1[mt][nt][rg] + acc2[mt][nt][rg] * (1.0f / 2048.0f);
  __syncthreads();

  const int bloc = t & 63, jg = t >> 6;
  const int bg = mblk * 64 + bloc;
  const float* arow = input
      ? addtab + (size_t)input[(size_t)bg * Ssz + tstep] * 2048
      : addtab;

  const int j0 = nblk * 32 + jg * 8;   // 8 j's per thread
  float* cp = cio + (size_t)bg * 512 + j0;
  float4 cv0 = *(const float4*)(cp);
  float4 cv1 = *(const float4*)(cp + 4);
  float cin[8] = {cv0.x, cv0.y, cv0.z, cv0.w, cv1.x, cv1.y, cv1.z, cv1.w};
  float cn[8], hv[8];
#pragma unroll
  for (int jj = 0; jj < 8; ++jj) {
    float4 gq = *(const float4*)(&Cst[bloc][jg * 32 + jj * 4]);
    float4 av = *(const float4*)(arow + (size_t)(j0 + jj) * 4);
    float gi = gq.x + av.x;
    float gf = gq.y + av.y;
    float gg = gq.z + av.z;
    float go = gq.w + av.w;
    float si = 1.0f / (1.0f + expf(-gi));
    float sf = 1.0f / (1.0f + expf(-gf));
    float sg = tanhf(gg);
    float so = 1.0f / (1.0f + expf(-go));
    float c2 = sf * cin[jj] + si * sg;
    cn[jj] = c2;
    hv[jj] = so * tanhf(c2);
  }
  *(float4*)(cp)     = make_float4(cn[0], cn[1], cn[2], cn[3]);
  *(float4*)(cp + 4) = make_float4(cn[4], cn[5], cn[6], cn[7]);

  f16x8 hi8, lo8;
#pragma unroll
  for (int jj = 0; jj < 8; ++jj) {
    f16 hi = (f16)hv[jj];
    hi8[jj] = hi;
    lo8[jj] = (f16)(hv[jj] - (float)hi);
  }
  const int kcH = j0 >> 5;             // 0..15
  const int kg = (j0 >> 3) & 3;
  size_t base = (((size_t)kcH * 128 + (bg >> 4)) * 64 + kg * 16 + (bg & 15)) * 8;
  *(f16x8*)(Aout + base)                       = hi8;  // kc 0..15: hi
  *(f16x8*)(Aout + base + (size_t)16 * 65536)  = lo8;  // kc 16..31: lo
}

// ---------------- batched blend MFMA: CH steps in one dispatch ---------------
// Dual-acc fp16x3 like gates.  Locality remap: bid = nblk*160 + mblkG so
// XCD = mblkG&7 -> all 8 nblk of one A-panel share an XCD; per-XCD A = 2.6MB
// (L2-resident), B resident across dispatches.  Grid 1280 -> 20 waves/CU.
__global__ __launch_bounds__(256) void blend_big(
    const f16* __restrict__ hChunk, const f16* __restrict__ Wb,
    float* __restrict__ outBase, int stepStride, int rowStride) {
  const int t = threadIdx.x, lane = t & 63, wid = t >> 6;
  const int wm = wid >> 1, wn = wid & 1;
  const int bid = blockIdx.x;
  const int nblk = bid / (CH * 32);    // 0..7   (32-w tiles)
  const int mblkG = bid % (CH * 32);   // 0..159; xcd = mblkG & 7
  const int s = mblkG >> 5;            // step within chunk
  const int mblkL = mblkG & 31;
  const f16* Ab = hChunk + (size_t)s * GFRAGC2
                + (size_t)(mblkL * 4 + wm * 2) * 512 + lane * 8;
  const f16* Bb = Wb + (size_t)(nblk * 2 + wn) * 512 + lane * 8;

  f32x4 acc1[2], acc2[2];
  {
    f32x4 z = {0.f, 0.f, 0.f, 0.f};
    acc1[0] = z; acc1[1] = z; acc2[0] = z; acc2[1] = z;
  }
  f16x8 pah[2], pal[2], pbh, pbl, qah[2], qal[2], qbh, qbl;

#define BLOAD(AH_, AL_, BH_, BL_, ki_)                                        \
  {                                                                           \
    const f16* ak = Ab + (size_t)(ki_)*65536;                                 \
    const f16* bk = Bb + (size_t)(ki_)*8192;                                  \
    _Pragma("unroll")                                                         \
    for (int q = 0; q < 2; ++q) {                                             \
      AH_[q] = *(const f16x8*)(ak + q * 512);                                 \
      AL_[q] = *(const f16x8*)(ak + (size_t)16 * 65536 + q * 512);            \
    }                                                                         \
    BH_ = *(const f16x8*)(bk);                                                \
    BL_ = *(const f16x8*)(bk + (size_t)16 * 8192);                            \
  }
#define BMM(AH_, AL_, BH_, BL_)                                               \
  {                                                                           \
    _Pragma("unroll")                                                         \
    for (int mt = 0; mt < 2; ++mt)                                            \
      acc1[mt] = __builtin_amdgcn_mfma_f32_16x16x32_f16(                      \
          AH_[mt], BH_, acc1[mt], 0, 0, 0);                                   \
    _Pragma("unroll")                                                         \
    for (int mt = 0; mt < 2; ++mt)                                            \
      acc1[mt] = __builtin_amdgcn_mfma_f32_16x16x32_f16(                      \
          AL_[mt], BH_, acc1[mt], 0, 0, 0);                                   \
    _Pragma("unroll")                                                         \
    for (int mt = 0; mt < 2; ++mt)                                            \
      acc2[mt] = __builtin_amdgcn_mfma_f32_16x16x32_f16(                      \
          AH_[mt], BL_, acc2[mt], 0, 0, 0);                                   \
  }

  BLOAD(pah, pal, pbh, pbl, 0)
#pragma unroll 1
  for (int ki = 0; ki < KI; ki += 2) {
    BLOAD(qah, qal, qbh, qbl, ki + 1)
    BMM(pah, pal, pbh, pbl)
    if (ki + 2 < KI) BLOAD(pah, pal, pbh, pbl, ki + 2)
    BMM(qah, qal, qbh, qbl)
  }
#undef BLOAD
#undef BMM

  const int r = lane & 15, rg4 = (lane >> 4) * 4;
  float* ob = outBase + (size_t)s * stepStride;
#pragma unroll
  for (int mt = 0; mt < 2; ++mt)
#pragma unroll
    for (int rg = 0; rg < 4; ++rg) {
      int b = mblkL * 64 + wm * 32 + mt * 16 + rg4 + rg;
      int w = nblk * 32 + wn * 16 + r;
      ob[(size_t)b * rowStride + w] = acc1[mt][rg] + acc2[mt][rg] * (1.0f / 2048.0f);
    }
}

// ---------------- decoder c0 = last encoder h (reconstruct hi+lo) ------------
__global__ __launch_bounds__(256) void dec_cinit(const f16* __restrict__ hE,
                                                 float* __restrict__ cD) {
  int idx = blockIdx.x * 256 + threadIdx.x;  // < 2048*512
  int b = idx >> 9, j = idx & 511;
  size_t base = (((size_t)(j >> 5) * 128 + (b >> 4)) * 64
                 + ((j >> 3) & 3) * 16 + (b & 15)) * 8 + (j & 7);
  cD[idx] = (float)hE[base] + (float)hE[base + (size_t)16 * 65536];
}

// ---------------- scores + log_softmax + gumbel sample + mask ----------------
__global__ __launch_bounds__(256) void scores_sample(
    const float* __restrict__ b1, const float* __restrict__ b2,
    const float* __restrict__ vt, unsigned long long* __restrict__ mask,
    float* __restrict__ probs, float* __restrict__ tour,
    int stepk, unsigned kA, unsigned kB) {
  __shared__ float b2s[256];
  __shared__ float vts[256];
  __shared__ float sc[52];
  const int t = threadIdx.x, b = blockIdx.x;
  b2s[t] = b2[(size_t)b * Wsz + t];
  vts[t] = vt[t];
  __syncthreads();
  const int wave = t >> 6, lane = t & 63;
  for (int s = wave; s < Ssz; s += 4) {
    const float* row = b1 + ((size_t)b * Ssz + s) * Wsz;
    float v = 0.f;
#pragma unroll
    for (int q = 0; q < 4; ++q) {
      int w = lane + 64 * q;
      v += vts[w] * tanhf(row[w] + b2s[w]);
    }
    for (int off = 32; off; off >>= 1) v += __shfl_xor(v, off);
    if (lane == 0) sc[s] = v;
  }
  __syncthreads();
  if (wave == 0) {
    unsigned long long m = mask[b];
    float x = (lane < Ssz) ? sc[lane] : -INFINITY;
    if (lane < Ssz && ((m >> lane) & 1ull)) x = -100000.0f;
    float mv = x;
    for (int off = 32; off; off >>= 1) mv = fmaxf(mv, __shfl_xor(mv, off));
    float sh = x - mv;
    float e = (lane < Ssz) ? expf(sh) : 0.f;
    float ssum = e;
    for (int off = 32; off; off >>= 1) ssum += __shfl_xor(ssum, off);
    float lg = logf(ssum);
    float logp = sh - lg;
    if (lane < Ssz) probs[(size_t)b * (Lsz * Ssz) + stepk * Ssz + lane] = logp;

    float val = -INFINITY;
    if (lane < Ssz) {
      unsigned j = (unsigned)(b * Ssz + lane);
      unsigned o0, o1, bits;
#if JAX_THREEFRY_PARTITIONABLE
      threefry2x32_hd(kA, kB, 0u, j, o0, o1);
      bits = o0 ^ o1;
#else
      if (j < 51200u) { threefry2x32_hd(kA, kB, j, j + 51200u, o0, o1); bits = o0; }
      else           { threefry2x32_hd(kA, kB, j - 51200u, j, o0, o1); bits = o1; }
#endif
      float f = __uint_as_float((bits >> 9) | 0x3F800000u) - 1.0f;
      float u = fmaxf(1.17549435e-38f, f + 1.17549435e-38f);
      val = logp - logf(-logf(u));
    }
    int idx = lane;
    for (int off = 32; off; off >>= 1) {
      float ov = __shfl_xor(val, off);
      int oi = __shfl_xor(idx, off);
      if (ov > val || (ov == val && oi < idx)) { val = ov; idx = oi; }
    }
    if (lane == 0) {
      tour[(size_t)b * Lsz + stepk] = (float)idx;
      mask[b] = m | (1ull << idx);
    }
  }
}

extern "C" void kernel_launch(void* const* d_in, const int* in_sizes, int n_in,
                              void* d_out, int out_size, void* d_ws, size_t ws_size,
                              hipStream_t stream) {
  (void)in_sizes; (void)n_in; (void)out_size; (void)ws_size;
  const int*   input = (const int*)d_in[0];
  const float* emb   = (const float*)d_in[1];
  const float* eWih  = (const float*)d_in[2];
  const float* eWhh  = (const float*)d_in[3];
  const float* ebih  = (const float*)d_in[4];
  const float* ebhh  = (const float*)d_in[5];
  /* d_in[6] dec_Wih unused: decoder input is always zero */
  const float* dWhh  = (const float*)d_in[7];
  const float* dbih  = (const float*)d_in[8];
  const float* dbhh  = (const float*)d_in[9];
  const float* W1    = (const float*)d_in[10];
  const float* W2    = (const float*)d_in[11];
  const float* vt    = (const float*)d_in[12];
  float* outF = (float*)d_out;

  float* wsf = (float*)d_ws;
  size_t o = 0;
  const size_t BFRAG = (size_t)32 * 16 * 512;   // f16 count (blend W pack)
  f16* BfE = (f16*)(wsf + o); o += GFRAGC2 / 2;  // enc gates W pack (4MB)
  f16* BfD = (f16*)(wsf + o); o += GFRAGC2 / 2;  // dec gates W pack
  f16* Bb1 = (f16*)(wsf + o); o += BFRAG / 2;    // W1 blend pack
  f16* Bb2 = (f16*)(wsf + o); o += BFRAG / 2;    // W2 blend pack
  float* encInP = wsf + o; o += (size_t)Vsz * 2048;
  float* dbiasP = wsf + o; o += 2048;
  f16* hZero = (f16*)(wsf + o); o += GFRAGC2 / 2;          // zero h frags
  f16* hBuf  = (f16*)(wsf + o); o += CH * (GFRAGC2 / 2);   // CH rolling h frags
  float* cE  = wsf + o; o += (size_t)Bsz * Hsz;            // enc c, then dec c
  float* b2c = wsf + o; o += (size_t)CH * Bsz * Wsz;       // dec b2 chunk
  float* b1  = wsf + o; o += (size_t)Bsz * Ssz * Wsz;
  unsigned long long* maskp = (unsigned long long*)(wsf + o); o += Bsz * 2;

  hipMemsetAsync(hZero, 0, GFRAGC2 * 2, stream);
  hipMemsetAsync(cE, 0, (size_t)Bsz * Hsz * 4, stream);
  hipMemsetAsync(maskp, 0, (size_t)Bsz * 8, stream);

  prep_gfrag<<<128 * 32, 512, 0, stream>>>(eWhh, BfE);
  prep_gfrag<<<128 * 32, 512, 0, stream>>>(dWhh, BfD);
  prep_bfrag<<<16 * 32, 512, 0, stream>>>(W1, Bb1);
  prep_bfrag<<<16 * 32, 512, 0, stream>>>(W2, Bb2);
  prep_encin<<<(Vsz * 2048) / 4, 256, 0, stream>>>(emb, eWih, ebih, ebhh, encInP);
  prep_dbias<<<8, 256, 0, stream>>>(dbih, dbhh, dbiasP);

  // host-side: step keys = jax.random.split(jax.random.key(42), 50)
  unsigned kAh[Lsz], kBh[Lsz];
  for (int k = 0; k < Lsz; ++k) {
#if JAX_THREEFRY_PARTITIONABLE
    threefry2x32_hd(0u, 42u, 0u, (unsigned)k, kAh[k], kBh[k]);
#else
    unsigned a0, a1, c0, c1;
    if (k < 25) {
      threefry2x32_hd(0u, 42u, 2u * k,      2u * k + 50u, a0, a1); kAh[k] = a0;
      threefry2x32_hd(0u, 42u, 2u * k + 1u, 2u * k + 51u, c0, c1); kBh[k] = c0;
    } else {
      threefry2x32_hd(0u, 42u, 2u * k - 50u, 2u * k,      a0, a1); kAh[k] = a1;
      threefry2x32_hd(0u, 42u, 2u * k - 49u, 2u * k + 1u, c0, c1); kBh[k] = c1;
    }
#endif
  }

  const size_t GF = GFRAGC2;  // f16 stride per step buffer

  // encoder: CH gates steps into rolling frag buffers, then one batched blend
  for (int c = 0; c < Ssz / CH; ++c) {
    for (int s = 0; s < CH; ++s) {
      int t = c * CH + s;
      const f16* in = (t == 0) ? hZero : hBuf + (size_t)((t - 1) % CH) * GF;
      gates_mfma<<<512, 256, 0, stream>>>(in, BfE, encInP, input, t,
                                          hBuf + (size_t)s * GF, cE);
    }
    blend_big<<<8 * CH * 32, 256, 0, stream>>>(hBuf, Bb1,
                                               b1 + (size_t)(c * CH) * Wsz,
                                               Wsz, Ssz * Wsz);
  }
  // decoder init: c0 = last encoder h (hi+lo), h0 = 0, mask = 0
  dec_cinit<<<(Bsz * Hsz) / 256, 256, 0, stream>>>(
      hBuf + (size_t)((Ssz - 1) % CH) * GF, cE);

  // decoder: gates x CH -> batched blend -> scores x CH (serial mask chain)
  for (int c = 0; c < Lsz / CH; ++c) {
    for (int s = 0; s < CH; ++s) {
      int k = c * CH + s;
      const f16* in = (k == 0) ? hZero : hBuf + (size_t)((k - 1) % CH) * GF;
      gates_mfma<<<512, 256, 0, stream>>>(in, BfD, dbiasP, nullptr, 0,
                                          hBuf + (size_t)s * GF, cE);
    }
    blend_big<<<8 * CH * 32, 256, 0, stream>>>(hBuf, Bb2, b2c,
                                               Bsz * Wsz, Wsz);
    for (int s = 0; s < CH; ++s) {
      int k = c * CH + s;
      scores_sample<<<Bsz, 256, 0, stream>>>(b1, b2c + (size_t)s * Bsz * Wsz,
                                             vt, maskp, outF,
                                             outF + (size_t)Bsz * Lsz * Ssz,
                                             k, kAh[k], kBh[k]);
    }
  }
}